// Round 2
// baseline (2136.973 us; speedup 1.0000x reference)
//
#include <hip/hip_runtime.h>
#include <hip/hip_bf16.h>

#define N_NODES 100000
#define N_EDGES 600000
#define DIM     128
#define N_REL   8
#define N_GRAPH 64
#define N_LAYER 3
#define NR      (N_NODES * N_REL)   // 800000
#define NB1     782                 // ceil(NR / 1024)

typedef __attribute__((ext_vector_type(8))) short short8;
typedef __attribute__((ext_vector_type(4))) float float4v;

__device__ __forceinline__ float bflo(unsigned int u) {
    return __builtin_bit_cast(float, u << 16);
}
__device__ __forceinline__ float bfhi(unsigned int u) {
    return __builtin_bit_cast(float, u & 0xffff0000u);
}
__device__ __forceinline__ unsigned short f2bf(float f) {
    unsigned int u = __builtin_bit_cast(unsigned int, f);
    u += 0x7fffu + ((u >> 16) & 1u);          // RNE
    return (unsigned short)(u >> 16);
}
__device__ __forceinline__ unsigned int pack2(float a, float b) {
    return (unsigned int)f2bf(a) | ((unsigned int)f2bf(b) << 16);
}
// XOR-swizzled granule index: rows of 128 shorts = 16 granules of 16 B.
__device__ __forceinline__ int gswz(int row, int g) {
    return row * 16 + (g ^ (row & 15));
}

// ---------------- utility: zero int buffer ----------------
__global__ void k_zero(int* __restrict__ p, int n) {
    int i = blockIdx.x * 256 + threadIdx.x;
    if (i < n) p[i] = 0;
}

// ---------------- counting sort of edges by seg = rel*N + dst ----------------
__global__ void k_hist(const int* __restrict__ ei, const int* __restrict__ et,
                       int* __restrict__ counts) {
    int e = blockIdx.x * 256 + threadIdx.x;
    if (e < N_EDGES) {
        int seg = et[e] * N_NODES + ei[N_EDGES + e];
        atomicAdd(&counts[seg], 1);
    }
}

__global__ __launch_bounds__(256) void k_scan1(const int* __restrict__ cnts,
                                               int* __restrict__ part,
                                               int* __restrict__ bsum) {
    __shared__ int sh[256];
    int t = threadIdx.x;
    int base = blockIdx.x * 1024 + t * 4;
    int v0 = (base + 0 < NR) ? cnts[base + 0] : 0;
    int v1 = (base + 1 < NR) ? cnts[base + 1] : 0;
    int v2 = (base + 2 < NR) ? cnts[base + 2] : 0;
    int v3 = (base + 3 < NR) ? cnts[base + 3] : 0;
    int tot = v0 + v1 + v2 + v3;
    sh[t] = tot;
    __syncthreads();
    for (int off = 1; off < 256; off <<= 1) {
        int x = (t >= off) ? sh[t - off] : 0;
        __syncthreads();
        sh[t] += x;
        __syncthreads();
    }
    int exc = sh[t] - tot;
    if (base + 0 < NR) part[base + 0] = exc;
    if (base + 1 < NR) part[base + 1] = exc + v0;
    if (base + 2 < NR) part[base + 2] = exc + v0 + v1;
    if (base + 3 < NR) part[base + 3] = exc + v0 + v1 + v2;
    if (t == 255) bsum[blockIdx.x] = sh[t];
}

__global__ __launch_bounds__(1024) void k_scan2(int* __restrict__ bsum, int nb) {
    __shared__ int sh[1024];
    int t = threadIdx.x;
    int v = (t < nb) ? bsum[t] : 0;
    sh[t] = v;
    __syncthreads();
    for (int off = 1; off < 1024; off <<= 1) {
        int x = (t >= off) ? sh[t - off] : 0;
        __syncthreads();
        sh[t] += x;
        __syncthreads();
    }
    if (t < nb) bsum[t] = sh[t] - v;   // exclusive block offsets
}

__global__ void k_scan3(const int* __restrict__ part, const int* __restrict__ bsum,
                        int* __restrict__ rowptr, int* __restrict__ cursor) {
    int i = blockIdx.x * 256 + threadIdx.x;
    if (i < NR) {
        int v = part[i] + bsum[i >> 10];
        rowptr[i] = v;
        cursor[i] = v;
    }
    if (i == 0) rowptr[NR] = N_EDGES;
}

__global__ void k_scatter(const int* __restrict__ ei, const int* __restrict__ et,
                          int* __restrict__ cursor, int2* __restrict__ edges) {
    int e = blockIdx.x * 256 + threadIdx.x;
    if (e < N_EDGES) {
        int src = ei[e], dst = ei[N_EDGES + e];
        int seg = et[e] * N_NODES + dst;
        int p = atomicAdd(&cursor[seg], 1);
        edges[p] = make_int2(src, dst);
    }
}

// ---------------- x0 = node_emb[node_type], stored bf16x2 ----------------
__global__ void k_gather(const int* __restrict__ nt, const float* __restrict__ emb,
                         unsigned int* __restrict__ x2) {
    int gid = blockIdx.x * 256 + threadIdx.x;
    if (gid < N_NODES * 64) {
        int n = gid >> 6, c2 = gid & 63;
        const float* row = emb + (size_t)nt[n] * DIM + c2 * 2;
        x2[gid] = pack2(row[0], row[1]);
    }
}

// ---------------- weight prep: WT[l][chunk][n][k] bf16 (transposed) ----------------
__global__ void k_wprep(const float* __restrict__ relw, const float* __restrict__ rootw,
                        unsigned short* __restrict__ WT) {
    int gid = blockIdx.x * 256 + threadIdx.x;
    if (gid < N_LAYER * 9 * 16384) {
        int l = gid / (9 * 16384);
        int rem = gid - l * 9 * 16384;
        int c = rem >> 14;
        int idx = rem & 16383;
        int n = idx >> 7, k = idx & 127;
        float w = (c < 8) ? relw[(((size_t)l * 8 + c) * 128 + k) * 128 + n]
                          : rootw[((size_t)l * 128 + k) * 128 + n];
        WT[gid] = f2bf(w);
    }
}

// ---------------- fused RGCN layer: edge-parallel aggregate + MFMA GEMM ----------------
// out[n,:] = relu( sum_r mean_r[n,:] @ Wrel[r] + x[n,:] @ Wroot + bias )
#define BM 64
__global__ __launch_bounds__(256) void k_layer(
    const unsigned int* __restrict__ xin,   // [N][64] bf16x2
    unsigned int* __restrict__ xout,        // [N][64] bf16x2
    const int* __restrict__ rowptr,         // [NR+1], seg = rel*N + dst
    const int2* __restrict__ edges,         // [E] sorted by seg: {src, dst}
    const unsigned short* __restrict__ WT,  // [9][128(n)][128(k)] bf16
    const float* __restrict__ bias)         // [128]
{
    // accA (fp32 accumulate, 32 KB) is aliased as the bf16 A tile (swizzled).
    __shared__ __align__(16) float accA[BM * 128];
    __shared__ __align__(16) unsigned int Bls[128 * 64];   // swizzled granules, 32 KB
    __shared__ int ldsRP[BM + 1];

    const int t = threadIdx.x;
    const int wv = t >> 6, lane = t & 63;
    const int quad = lane >> 4, l15 = lane & 15;
    const int m0 = blockIdx.x * BM;

    unsigned int* Au = (unsigned int*)accA;
    const unsigned short* Abfs = (const unsigned short*)accA;
    const unsigned short* Bbfs = (const unsigned short*)Bls;
    float4* A4 = (float4*)accA;
    uint4* B4 = (uint4*)Bls;

    float4v acc[8];
#pragma unroll
    for (int nt = 0; nt < 8; ++nt) {
        float bc = bias[nt * 16 + l15];
        acc[nt] = (float4v){bc, bc, bc, bc};
    }

    for (int c = 0; c < 8; ++c) {
        __syncthreads();   // previous chunk's MFMA done with Abf/Bls
        // ---- phase Z: zero accA, load rowptr slice, stage B chunk ----
#pragma unroll
        for (int i = 0; i < 16; ++i)
            A4[t + 256 * i] = (float4){0.f, 0.f, 0.f, 0.f};
        if (t < BM + 1) {
            int idx = c * N_NODES + m0 + t;
            int cap = c * N_NODES + N_NODES;
            ldsRP[t] = rowptr[idx < cap ? idx : cap];
        }
        {
            const uint4* Wc = (const uint4*)(WT + c * 16384);
#pragma unroll
            for (int i = 0; i < 8; ++i) {
                int idx = t + 256 * i;            // granule id 0..2047
                int n = idx >> 4, g = idx & 15;
                B4[gswz(n, g)] = Wc[idx];
            }
        }
        __syncthreads();
        // ---- phase E: edge-parallel accumulate (wave per edge, unroll 4) ----
        {
            int s = ldsRP[0], e64 = ldsRP[BM];
            for (int j0 = s + wv * 4; j0 < e64; j0 += 16) {
                unsigned int u[4];
                int rw[4];
                int nv = e64 - j0;               // wave-uniform
#pragma unroll
                for (int q = 0; q < 4; ++q) {
                    if (q < nv) {
                        int2 ed = edges[j0 + q];
                        rw[q] = ed.y - m0;
                        u[q] = xin[(size_t)ed.x * 64 + lane];
                    }
                }
#pragma unroll
                for (int q = 0; q < 4; ++q) {
                    if (q < nv) {
                        atomicAdd(&accA[rw[q] * 128 + lane * 2],     bflo(u[q]));
                        atomicAdd(&accA[rw[q] * 128 + lane * 2 + 1], bfhi(u[q]));
                    }
                }
            }
        }
        __syncthreads();
        // ---- phase C: fp32 -> mean -> bf16 (in place, read-all then write-all) ----
        float va[16], vb[16], iv[16];
#pragma unroll
        for (int i = 0; i < 16; ++i) {
            int ml = wv + 4 * i;
            float2 p = *(const float2*)&accA[ml * 128 + lane * 2];
            va[i] = p.x; vb[i] = p.y;
            int cnt = ldsRP[ml + 1] - ldsRP[ml];
            iv[i] = (cnt > 0) ? 1.0f / (float)cnt : 0.0f;
        }
        __syncthreads();
#pragma unroll
        for (int i = 0; i < 16; ++i) {
            int ml = wv + 4 * i;
            Au[ml * 64 + (((lane >> 2) ^ (ml & 15)) << 2) + (lane & 3)] =
                pack2(va[i] * iv[i], vb[i] * iv[i]);
        }
        __syncthreads();
        // ---- phase M: MFMA 4 K-steps x 8 N-tiles ----
#pragma unroll
        for (int kk = 0; kk < 4; ++kk) {
            int g = kk * 4 + quad;
            short8 a = *(const short8*)(Abfs + gswz(wv * 16 + l15, g) * 8);
#pragma unroll
            for (int nt = 0; nt < 8; ++nt) {
                short8 b = *(const short8*)(Bbfs + gswz(nt * 16 + l15, g) * 8);
                acc[nt] = __builtin_amdgcn_mfma_f32_16x16x32_bf16(a, b, acc[nt], 0, 0, 0);
            }
        }
    }
    // ---- root chunk (c = 8): A = xin rows directly ----
    __syncthreads();
    {
        const uint4* Wc = (const uint4*)(WT + 8 * 16384);
#pragma unroll
        for (int i = 0; i < 8; ++i) {
            int idx = t + 256 * i;
            int n = idx >> 4, g = idx & 15;
            B4[gswz(n, g)] = Wc[idx];
        }
#pragma unroll
        for (int i = 0; i < 16; ++i) {
            int ml = wv + 4 * i;
            int m = m0 + ml;
            unsigned int v = (m < N_NODES) ? xin[(size_t)m * 64 + lane] : 0u;
            Au[ml * 64 + (((lane >> 2) ^ (ml & 15)) << 2) + (lane & 3)] = v;
        }
    }
    __syncthreads();
#pragma unroll
    for (int kk = 0; kk < 4; ++kk) {
        int g = kk * 4 + quad;
        short8 a = *(const short8*)(Abfs + gswz(wv * 16 + l15, g) * 8);
#pragma unroll
        for (int nt = 0; nt < 8; ++nt) {
            short8 b = *(const short8*)(Bbfs + gswz(nt * 16 + l15, g) * 8);
            acc[nt] = __builtin_amdgcn_mfma_f32_16x16x32_bf16(a, b, acc[nt], 0, 0, 0);
        }
    }
    // ---- epilogue: relu, store bf16 ----
    unsigned short* outs = (unsigned short*)xout;
#pragma unroll
    for (int nt = 0; nt < 8; ++nt) {
        int colg = nt * 16 + l15;
#pragma unroll
        for (int i = 0; i < 4; ++i) {
            int row = m0 + wv * 16 + quad * 4 + i;
            if (row < N_NODES) {
                float v = acc[nt][i];
                v = v > 0.f ? v : 0.f;
                outs[(size_t)row * 128 + colg] = f2bf(v);
            }
        }
    }
}

// ---------------- global mean pool (batch is sorted) ----------------
__global__ __launch_bounds__(256) void k_pool(const unsigned int* __restrict__ x2,
                                              const int* __restrict__ batch,
                                              float* __restrict__ gsum,
                                              int* __restrict__ gcnt) {
    int wv = threadIdx.x >> 6, lane = threadIdx.x & 63;
    int cid = blockIdx.x * 4 + wv;
    int n0 = cid * 512;
    if (n0 >= N_NODES) return;
    int n1 = n0 + 512;
    if (n1 > N_NODES) n1 = N_NODES;
    float a0 = 0.f, a1 = 0.f;
    int run = 0;
    int cur = batch[n0];
    for (int n = n0; n < n1; ++n) {
        int b = batch[n];
        if (b != cur) {
            atomicAdd(&gsum[cur * 128 + lane * 2], a0);
            atomicAdd(&gsum[cur * 128 + lane * 2 + 1], a1);
            if (lane == 0) atomicAdd(&gcnt[cur], run);
            a0 = a1 = 0.f;
            run = 0;
            cur = b;
        }
        unsigned int u = x2[(size_t)n * 64 + lane];
        a0 += bflo(u);
        a1 += bfhi(u);
        ++run;
    }
    atomicAdd(&gsum[cur * 128 + lane * 2], a0);
    atomicAdd(&gsum[cur * 128 + lane * 2 + 1], a1);
    if (lane == 0) atomicAdd(&gcnt[cur], run);
}

// ---------------- MLP heads (fp32) ----------------
__global__ __launch_bounds__(128) void k_heads(
    const float* __restrict__ gsum, const int* __restrict__ gcnt,
    const float* __restrict__ rw1, const float* __restrict__ rb1,
    const float* __restrict__ rw2, const float* __restrict__ rb2,
    const float* __restrict__ sw1, const float* __restrict__ sb1,
    const float* __restrict__ sw2, const float* __restrict__ sb2,
    float* __restrict__ out) {
    __shared__ float g[128];
    __shared__ float parts[2];
    int b = blockIdx.x, t = threadIdx.x;
    int c = gcnt[b];
    float invc = 1.0f / (float)(c > 0 ? c : 1);
    g[t] = gsum[b * 128 + t] * invc;
    __syncthreads();
    float acc = rb1[t];
    for (int d = 0; d < 128; ++d) acc += g[d] * rw1[d * 128 + t];
    float h = acc > 0.f ? acc : 0.f;
    float p = h * rw2[t];
    for (int o = 32; o > 0; o >>= 1) p += __shfl_down(p, o);
    if ((t & 63) == 0) parts[t >> 6] = p;
    __syncthreads();
    if (t == 0) out[b] = parts[0] + parts[1] + rb2[0];
    __syncthreads();
    acc = sb1[t];
    for (int d = 0; d < 128; ++d) acc += g[d] * sw1[d * 128 + t];
    h = acc > 0.f ? acc : 0.f;
    p = h * sw2[t];
    for (int o = 32; o > 0; o >>= 1) p += __shfl_down(p, o);
    if ((t & 63) == 0) parts[t >> 6] = p;
    __syncthreads();
    if (t == 0) out[64 + b] = parts[0] + parts[1] + sb2[0];
}

extern "C" void kernel_launch(void* const* d_in, const int* in_sizes, int n_in,
                              void* d_out, int out_size, void* d_ws, size_t ws_size,
                              hipStream_t stream) {
    const int*   node_type  = (const int*)d_in[0];
    const int*   edge_index = (const int*)d_in[1];
    const int*   edge_type  = (const int*)d_in[2];
    const int*   batch      = (const int*)d_in[3];
    const float* node_emb   = (const float*)d_in[4];
    const float* rel_w      = (const float*)d_in[5];
    const float* root_w     = (const float*)d_in[6];
    const float* bias       = (const float*)d_in[7];
    const float* rw1        = (const float*)d_in[8];
    const float* rb1        = (const float*)d_in[9];
    const float* rw2        = (const float*)d_in[10];
    const float* rb2        = (const float*)d_in[11];
    const float* sw1        = (const float*)d_in[12];
    const float* sb1        = (const float*)d_in[13];
    const float* sw2        = (const float*)d_in[14];
    const float* sb2        = (const float*)d_in[15];
    float* out = (float*)d_out;

    char* ws = (char*)d_ws;
    size_t off = 0;
    auto alloc = [&](size_t bytes) -> void* {
        void* p = ws + off;
        off += (bytes + 255) & ~(size_t)255;
        return p;
    };
    unsigned int*   xa     = (unsigned int*)alloc((size_t)N_NODES * 64 * 4);
    unsigned int*   xb     = (unsigned int*)alloc((size_t)N_NODES * 64 * 4);
    int*            rowptr = (int*)alloc((size_t)(NR + 1) * 4);
    int*            cursor = (int*)alloc((size_t)NR * 4);   // also scan "part" temp
    int*            counts = (int*)alloc((size_t)NR * 4);
    int2*           edges  = (int2*)alloc((size_t)N_EDGES * 8);
    int*            bsum   = (int*)alloc(1024 * 4);
    unsigned short* WT     = (unsigned short*)alloc((size_t)N_LAYER * 9 * 16384 * 2);
    float*          gsum   = (float*)alloc((64 * 128 + 64) * 4);
    int*            gcnt   = (int*)(gsum + 64 * 128);
    if (off > ws_size) return;   // workspace insufficient — fail visibly

    // edge sort (counting sort by rel*N + dst)
    k_zero<<<(NR + 255) / 256, 256, 0, stream>>>(counts, NR);
    k_zero<<<(64 * 128 + 64 + 255) / 256, 256, 0, stream>>>((int*)gsum, 64 * 128 + 64);
    k_hist<<<(N_EDGES + 255) / 256, 256, 0, stream>>>(edge_index, edge_type, counts);
    k_scan1<<<NB1, 256, 0, stream>>>(counts, cursor, bsum);
    k_scan2<<<1, 1024, 0, stream>>>(bsum, NB1);
    k_scan3<<<(NR + 255) / 256, 256, 0, stream>>>(cursor, bsum, rowptr, cursor);
    k_scatter<<<(N_EDGES + 255) / 256, 256, 0, stream>>>(edge_index, edge_type, cursor, edges);

    // x0 gather + weight prep
    k_gather<<<(N_NODES * 64 + 255) / 256, 256, 0, stream>>>(node_type, node_emb, xa);
    k_wprep<<<(N_LAYER * 9 * 16384 + 255) / 256, 256, 0, stream>>>(rel_w, root_w, WT);

    // 3 fused RGCN layers
    const int mblocks = (N_NODES + BM - 1) / BM;
    k_layer<<<mblocks, 256, 0, stream>>>(xa, xb, rowptr, edges, WT + 0 * 9 * 16384, bias + 0 * 128);
    k_layer<<<mblocks, 256, 0, stream>>>(xb, xa, rowptr, edges, WT + 1 * 9 * 16384, bias + 1 * 128);
    k_layer<<<mblocks, 256, 0, stream>>>(xa, xb, rowptr, edges, WT + 2 * 9 * 16384, bias + 2 * 128);

    // pool + heads
    k_pool<<<(N_NODES + 2047) / 2048, 256, 0, stream>>>(xb, batch, gsum, gcnt);
    k_heads<<<64, 128, 0, stream>>>(gsum, gcnt, rw1, rb1, rw2, rb2,
                                    sw1, sb1, sw2, sb2, out);
}

// Round 3
// 2122.210 us; speedup vs baseline: 1.0070x; 1.0070x over previous
//
#include <hip/hip_runtime.h>
#include <hip/hip_bf16.h>

#define N_NODES 100000
#define N_EDGES 600000
#define DIM     128
#define N_REL   8
#define N_GRAPH 64
#define N_LAYER 3
#define NR      (N_NODES * N_REL)   // 800000
#define NB1     782                 // ceil(NR / 1024)

typedef __attribute__((ext_vector_type(8))) short short8;
typedef __attribute__((ext_vector_type(4))) float float4v;

__device__ __forceinline__ float bflo(unsigned int u) {
    return __builtin_bit_cast(float, u << 16);
}
__device__ __forceinline__ float bfhi(unsigned int u) {
    return __builtin_bit_cast(float, u & 0xffff0000u);
}
__device__ __forceinline__ unsigned short f2bf(float f) {
    unsigned int u = __builtin_bit_cast(unsigned int, f);
    u += 0x7fffu + ((u >> 16) & 1u);          // RNE
    return (unsigned short)(u >> 16);
}
__device__ __forceinline__ unsigned int pack2(float a, float b) {
    return (unsigned int)f2bf(a) | ((unsigned int)f2bf(b) << 16);
}
// XOR-swizzled granule index: rows of 128 shorts = 16 granules of 16 B.
__device__ __forceinline__ int gswz(int row, int g) {
    return row * 16 + (g ^ (row & 15));
}

// ---------------- utility: zero int buffer ----------------
__global__ void k_zero(int* __restrict__ p, int n) {
    int i = blockIdx.x * 256 + threadIdx.x;
    if (i < n) p[i] = 0;
}

// ---------------- counting sort of edges by seg = rel*N + dst ----------------
__global__ void k_hist(const int* __restrict__ ei, const int* __restrict__ et,
                       int* __restrict__ counts) {
    int e = blockIdx.x * 256 + threadIdx.x;
    if (e < N_EDGES) {
        int seg = et[e] * N_NODES + ei[N_EDGES + e];
        atomicAdd(&counts[seg], 1);
    }
}

__global__ __launch_bounds__(256) void k_scan1(const int* __restrict__ cnts,
                                               int* __restrict__ part,
                                               int* __restrict__ bsum) {
    __shared__ int sh[256];
    int t = threadIdx.x;
    int base = blockIdx.x * 1024 + t * 4;
    int v0 = (base + 0 < NR) ? cnts[base + 0] : 0;
    int v1 = (base + 1 < NR) ? cnts[base + 1] : 0;
    int v2 = (base + 2 < NR) ? cnts[base + 2] : 0;
    int v3 = (base + 3 < NR) ? cnts[base + 3] : 0;
    int tot = v0 + v1 + v2 + v3;
    sh[t] = tot;
    __syncthreads();
    for (int off = 1; off < 256; off <<= 1) {
        int x = (t >= off) ? sh[t - off] : 0;
        __syncthreads();
        sh[t] += x;
        __syncthreads();
    }
    int exc = sh[t] - tot;
    if (base + 0 < NR) part[base + 0] = exc;
    if (base + 1 < NR) part[base + 1] = exc + v0;
    if (base + 2 < NR) part[base + 2] = exc + v0 + v1;
    if (base + 3 < NR) part[base + 3] = exc + v0 + v1 + v2;
    if (t == 255) bsum[blockIdx.x] = sh[t];
}

__global__ __launch_bounds__(1024) void k_scan2(int* __restrict__ bsum, int nb) {
    __shared__ int sh[1024];
    int t = threadIdx.x;
    int v = (t < nb) ? bsum[t] : 0;
    sh[t] = v;
    __syncthreads();
    for (int off = 1; off < 1024; off <<= 1) {
        int x = (t >= off) ? sh[t - off] : 0;
        __syncthreads();
        sh[t] += x;
        __syncthreads();
    }
    if (t < nb) bsum[t] = sh[t] - v;   // exclusive block offsets
}

__global__ void k_scan3(const int* __restrict__ part, const int* __restrict__ bsum,
                        int* __restrict__ rowptr, int* __restrict__ cursor) {
    int i = blockIdx.x * 256 + threadIdx.x;
    if (i < NR) {
        int v = part[i] + bsum[i >> 10];
        rowptr[i] = v;
        cursor[i] = v;
    }
    if (i == 0) rowptr[NR] = N_EDGES;
}

__global__ void k_scatter(const int* __restrict__ ei, const int* __restrict__ et,
                          int* __restrict__ cursor, int2* __restrict__ edges) {
    int e = blockIdx.x * 256 + threadIdx.x;
    if (e < N_EDGES) {
        int src = ei[e], dst = ei[N_EDGES + e];
        int seg = et[e] * N_NODES + dst;
        int p = atomicAdd(&cursor[seg], 1);
        edges[p] = make_int2(src, dst);
    }
}

// ---------------- x0 = node_emb[node_type], stored bf16x2 ----------------
__global__ void k_gather(const int* __restrict__ nt, const float* __restrict__ emb,
                         unsigned int* __restrict__ x2) {
    int gid = blockIdx.x * 256 + threadIdx.x;
    if (gid < N_NODES * 64) {
        int n = gid >> 6, c2 = gid & 63;
        const float* row = emb + (size_t)nt[n] * DIM + c2 * 2;
        x2[gid] = pack2(row[0], row[1]);
    }
}

// ---------------- weight prep: WT[l][chunk][n][k] bf16 (transposed) ----------------
__global__ void k_wprep(const float* __restrict__ relw, const float* __restrict__ rootw,
                        unsigned short* __restrict__ WT) {
    int gid = blockIdx.x * 256 + threadIdx.x;
    if (gid < N_LAYER * 9 * 16384) {
        int l = gid / (9 * 16384);
        int rem = gid - l * 9 * 16384;
        int c = rem >> 14;
        int idx = rem & 16383;
        int n = idx >> 7, k = idx & 127;
        float w = (c < 8) ? relw[(((size_t)l * 8 + c) * 128 + k) * 128 + n]
                          : rootw[((size_t)l * 128 + k) * 128 + n];
        WT[gid] = f2bf(w);
    }
}

// ---------------- fused RGCN layer: edge-parallel aggregate + MFMA GEMM ----------------
// out[n,:] = relu( sum_r mean_r[n,:] @ Wrel[r] + x[n,:] @ Wroot + bias )
#define BM   64
#define ECAP 512
__global__ __launch_bounds__(256) void k_layer(
    const unsigned int* __restrict__ xin,   // [N][64] bf16x2
    unsigned int* __restrict__ xout,        // [N][64] bf16x2
    const int* __restrict__ rowptr,         // [NR+1], seg = rel*N + dst
    const int2* __restrict__ edges,         // [E] sorted by seg: {src, dst}
    const unsigned short* __restrict__ WT,  // [9][128(n)][128(k)] bf16
    const float* __restrict__ bias)         // [128]
{
    // accA (fp32 accumulate, 32 KB) is aliased as the bf16 A tile (swizzled).
    __shared__ __align__(16) float accA[BM * 128];         // 32 KB
    __shared__ __align__(16) unsigned int Bls[128 * 64];   // 32 KB swizzled
    __shared__ __align__(16) int2 ldsE[ECAP];              // 4 KB staged edges
    __shared__ int ldsRP[8 * 65];                          // 2080 B

    const int t = threadIdx.x;
    const int wv = t >> 6, lane = t & 63;
    const int quad = lane >> 4, l15 = lane & 15;
    const int m0 = blockIdx.x * BM;

    unsigned int* Au = (unsigned int*)accA;
    const unsigned short* Abfs = (const unsigned short*)accA;
    const unsigned short* Bbfs = (const unsigned short*)Bls;
    float4* A4 = (float4*)accA;
    uint4* B4 = (uint4*)Bls;
    const unsigned short* xs = (const unsigned short*)xin;

    // block-start: all relation rowptr slices (read once)
    for (int i = t; i < 8 * 65; i += 256) {
        int c = i / 65, r = i - c * 65;
        int row = m0 + r;
        if (row > N_NODES) row = N_NODES;
        ldsRP[i] = rowptr[c * N_NODES + row];
    }

    float4v acc[8];
#pragma unroll
    for (int nt = 0; nt < 8; ++nt) {
        float bc = bias[nt * 16 + l15];
        acc[nt] = (float4v){bc, bc, bc, bc};
    }

    for (int c = 0; c < 8; ++c) {
        __syncthreads();   // prev MFMA done with accA/Bls (and covers ldsRP init at c=0)
        // ---- phase Z: zero accA, stage B chunk, stage edge records ----
#pragma unroll
        for (int i = 0; i < 8; ++i)
            A4[t + 256 * i] = (float4){0.f, 0.f, 0.f, 0.f};
        {
            const uint4* Wc = (const uint4*)(WT + c * 16384);
#pragma unroll
            for (int i = 0; i < 8; ++i) {
                int idx = t + 256 * i;            // granule id 0..2047
                int n = idx >> 4, g = idx & 15;
                B4[gswz(n, g)] = Wc[idx];
            }
        }
        int sE = ldsRP[c * 65], eE = ldsRP[c * 65 + 64];
        int total = eE - sE;
        int nL = total < ECAP ? total : ECAP;
        for (int i = t; i < nL; i += 256) ldsE[i] = edges[sE + i];
        __syncthreads();
        // ---- phase E: edge-parallel accumulate (edge records from LDS, unroll 8) ----
        for (int j0 = wv * 8; j0 < nL; j0 += 32) {
            int nv = nL - j0;                    // wave-uniform
            unsigned int ua[8], ub[8];
            int rw[8];
#pragma unroll
            for (int q = 0; q < 8; ++q) {
                if (q < nv) {
                    int2 ed = ldsE[j0 + q];
                    rw[q] = ed.y - m0;
                    size_t base = (size_t)ed.x * 128;
                    ua[q] = xs[base + lane];
                    ub[q] = xs[base + 64 + lane];
                }
            }
#pragma unroll
            for (int q = 0; q < 8; ++q) {
                if (q < nv) {
                    atomicAdd(&accA[rw[q] * 128 + lane],      bflo(ua[q] << 16 >> 16 ? ua[q] : ua[q]) * 0.f + __builtin_bit_cast(float, ua[q] << 16));
                    atomicAdd(&accA[rw[q] * 128 + 64 + lane], __builtin_bit_cast(float, ub[q] << 16));
                }
            }
        }
        // rare fallback: edges beyond ECAP read from global
        for (int j0 = ECAP + wv * 4; j0 < total; j0 += 16) {
            int nv = total - j0;
#pragma unroll
            for (int q = 0; q < 4; ++q) {
                if (q < nv) {
                    int2 ed = edges[sE + j0 + q];
                    int rw = ed.y - m0;
                    size_t base = (size_t)ed.x * 128;
                    float fa = __builtin_bit_cast(float, (unsigned int)xs[base + lane] << 16);
                    float fb = __builtin_bit_cast(float, (unsigned int)xs[base + 64 + lane] << 16);
                    atomicAdd(&accA[rw * 128 + lane], fa);
                    atomicAdd(&accA[rw * 128 + 64 + lane], fb);
                }
            }
        }
        __syncthreads();
        // ---- phase C: fp32 -> mean -> bf16 (in place, read-all then write-all) ----
        float va[16], vb[16], iv[16];
#pragma unroll
        for (int i = 0; i < 16; ++i) {
            int ml = wv + 4 * i;
            float2 p = *(const float2*)&accA[ml * 128 + lane * 2];
            va[i] = p.x; vb[i] = p.y;
            int cnt = ldsRP[c * 65 + ml + 1] - ldsRP[c * 65 + ml];
            iv[i] = (cnt > 0) ? 1.0f / (float)cnt : 0.0f;
        }
        __syncthreads();
#pragma unroll
        for (int i = 0; i < 16; ++i) {
            int ml = wv + 4 * i;
            Au[ml * 64 + (((lane >> 2) ^ (ml & 15)) << 2) + (lane & 3)] =
                pack2(va[i] * iv[i], vb[i] * iv[i]);
        }
        __syncthreads();
        // ---- phase M: MFMA 4 K-steps x 8 N-tiles ----
#pragma unroll
        for (int kk = 0; kk < 4; ++kk) {
            int g = kk * 4 + quad;
            short8 a = *(const short8*)(Abfs + gswz(wv * 16 + l15, g) * 8);
#pragma unroll
            for (int nt = 0; nt < 8; ++nt) {
                short8 b = *(const short8*)(Bbfs + gswz(nt * 16 + l15, g) * 8);
                acc[nt] = __builtin_amdgcn_mfma_f32_16x16x32_bf16(a, b, acc[nt], 0, 0, 0);
            }
        }
    }
    // ---- root chunk (c = 8): A = xin rows directly ----
    __syncthreads();
    {
        const uint4* Wc = (const uint4*)(WT + 8 * 16384);
#pragma unroll
        for (int i = 0; i < 8; ++i) {
            int idx = t + 256 * i;
            int n = idx >> 4, g = idx & 15;
            B4[gswz(n, g)] = Wc[idx];
        }
#pragma unroll
        for (int i = 0; i < 16; ++i) {
            int ml = wv + 4 * i;
            int m = m0 + ml;
            unsigned int v = (m < N_NODES) ? xin[(size_t)m * 64 + lane] : 0u;
            Au[ml * 64 + (((lane >> 2) ^ (ml & 15)) << 2) + (lane & 3)] = v;
        }
    }
    __syncthreads();
#pragma unroll
    for (int kk = 0; kk < 4; ++kk) {
        int g = kk * 4 + quad;
        short8 a = *(const short8*)(Abfs + gswz(wv * 16 + l15, g) * 8);
#pragma unroll
        for (int nt = 0; nt < 8; ++nt) {
            short8 b = *(const short8*)(Bbfs + gswz(nt * 16 + l15, g) * 8);
            acc[nt] = __builtin_amdgcn_mfma_f32_16x16x32_bf16(a, b, acc[nt], 0, 0, 0);
        }
    }
    // ---- epilogue: relu, store bf16 ----
    unsigned short* outs = (unsigned short*)xout;
#pragma unroll
    for (int nt = 0; nt < 8; ++nt) {
        int colg = nt * 16 + l15;
#pragma unroll
        for (int i = 0; i < 4; ++i) {
            int row = m0 + wv * 16 + quad * 4 + i;
            if (row < N_NODES) {
                float v = acc[nt][i];
                v = v > 0.f ? v : 0.f;
                outs[(size_t)row * 128 + colg] = f2bf(v);
            }
        }
    }
}

// ---------------- global mean pool (batch is sorted) ----------------
__global__ __launch_bounds__(256) void k_pool(const unsigned int* __restrict__ x2,
                                              const int* __restrict__ batch,
                                              float* __restrict__ gsum,
                                              int* __restrict__ gcnt) {
    int wv = threadIdx.x >> 6, lane = threadIdx.x & 63;
    int cid = blockIdx.x * 4 + wv;
    int n0 = cid * 512;
    if (n0 >= N_NODES) return;
    int n1 = n0 + 512;
    if (n1 > N_NODES) n1 = N_NODES;
    float a0 = 0.f, a1 = 0.f;
    int run = 0;
    int cur = batch[n0];
    for (int n = n0; n < n1; ++n) {
        int b = batch[n];
        if (b != cur) {
            atomicAdd(&gsum[cur * 128 + lane * 2], a0);
            atomicAdd(&gsum[cur * 128 + lane * 2 + 1], a1);
            if (lane == 0) atomicAdd(&gcnt[cur], run);
            a0 = a1 = 0.f;
            run = 0;
            cur = b;
        }
        unsigned int u = x2[(size_t)n * 64 + lane];
        a0 += bflo(u);
        a1 += bfhi(u);
        ++run;
    }
    atomicAdd(&gsum[cur * 128 + lane * 2], a0);
    atomicAdd(&gsum[cur * 128 + lane * 2 + 1], a1);
    if (lane == 0) atomicAdd(&gcnt[cur], run);
}

// ---------------- MLP heads (fp32) ----------------
__global__ __launch_bounds__(128) void k_heads(
    const float* __restrict__ gsum, const int* __restrict__ gcnt,
    const float* __restrict__ rw1, const float* __restrict__ rb1,
    const float* __restrict__ rw2, const float* __restrict__ rb2,
    const float* __restrict__ sw1, const float* __restrict__ sb1,
    const float* __restrict__ sw2, const float* __restrict__ sb2,
    float* __restrict__ out) {
    __shared__ float g[128];
    __shared__ float parts[2];
    int b = blockIdx.x, t = threadIdx.x;
    int c = gcnt[b];
    float invc = 1.0f / (float)(c > 0 ? c : 1);
    g[t] = gsum[b * 128 + t] * invc;
    __syncthreads();
    float acc = rb1[t];
    for (int d = 0; d < 128; ++d) acc += g[d] * rw1[d * 128 + t];
    float h = acc > 0.f ? acc : 0.f;
    float p = h * rw2[t];
    for (int o = 32; o > 0; o >>= 1) p += __shfl_down(p, o);
    if ((t & 63) == 0) parts[t >> 6] = p;
    __syncthreads();
    if (t == 0) out[b] = parts[0] + parts[1] + rb2[0];
    __syncthreads();
    acc = sb1[t];
    for (int d = 0; d < 128; ++d) acc += g[d] * sw1[d * 128 + t];
    h = acc > 0.f ? acc : 0.f;
    p = h * sw2[t];
    for (int o = 32; o > 0; o >>= 1) p += __shfl_down(p, o);
    if ((t & 63) == 0) parts[t >> 6] = p;
    __syncthreads();
    if (t == 0) out[64 + b] = parts[0] + parts[1] + sb2[0];
}

extern "C" void kernel_launch(void* const* d_in, const int* in_sizes, int n_in,
                              void* d_out, int out_size, void* d_ws, size_t ws_size,
                              hipStream_t stream) {
    const int*   node_type  = (const int*)d_in[0];
    const int*   edge_index = (const int*)d_in[1];
    const int*   edge_type  = (const int*)d_in[2];
    const int*   batch      = (const int*)d_in[3];
    const float* node_emb   = (const float*)d_in[4];
    const float* rel_w      = (const float*)d_in[5];
    const float* root_w     = (const float*)d_in[6];
    const float* bias       = (const float*)d_in[7];
    const float* rw1        = (const float*)d_in[8];
    const float* rb1        = (const float*)d_in[9];
    const float* rw2        = (const float*)d_in[10];
    const float* rb2        = (const float*)d_in[11];
    const float* sw1        = (const float*)d_in[12];
    const float* sb1        = (const float*)d_in[13];
    const float* sw2        = (const float*)d_in[14];
    const float* sb2        = (const float*)d_in[15];
    float* out = (float*)d_out;

    char* ws = (char*)d_ws;
    size_t off = 0;
    auto alloc = [&](size_t bytes) -> void* {
        void* p = ws + off;
        off += (bytes + 255) & ~(size_t)255;
        return p;
    };
    unsigned int*   xa     = (unsigned int*)alloc((size_t)N_NODES * 64 * 4);
    unsigned int*   xb     = (unsigned int*)alloc((size_t)N_NODES * 64 * 4);
    int*            rowptr = (int*)alloc((size_t)(NR + 1) * 4);
    int*            cursor = (int*)alloc((size_t)NR * 4);   // also scan "part" temp
    int*            counts = (int*)alloc((size_t)NR * 4);
    int2*           edges  = (int2*)alloc((size_t)N_EDGES * 8);
    int*            bsum   = (int*)alloc(1024 * 4);
    unsigned short* WT     = (unsigned short*)alloc((size_t)N_LAYER * 9 * 16384 * 2);
    float*          gsum   = (float*)alloc((64 * 128 + 64) * 4);
    int*            gcnt   = (int*)(gsum + 64 * 128);
    if (off > ws_size) return;   // workspace insufficient — fail visibly

    // edge sort (counting sort by rel*N + dst)
    k_zero<<<(NR + 255) / 256, 256, 0, stream>>>(counts, NR);
    k_zero<<<(64 * 128 + 64 + 255) / 256, 256, 0, stream>>>((int*)gsum, 64 * 128 + 64);
    k_hist<<<(N_EDGES + 255) / 256, 256, 0, stream>>>(edge_index, edge_type, counts);
    k_scan1<<<NB1, 256, 0, stream>>>(counts, cursor, bsum);
    k_scan2<<<1, 1024, 0, stream>>>(bsum, NB1);
    k_scan3<<<(NR + 255) / 256, 256, 0, stream>>>(cursor, bsum, rowptr, cursor);
    k_scatter<<<(N_EDGES + 255) / 256, 256, 0, stream>>>(edge_index, edge_type, cursor, edges);

    // x0 gather + weight prep
    k_gather<<<(N_NODES * 64 + 255) / 256, 256, 0, stream>>>(node_type, node_emb, xa);
    k_wprep<<<(N_LAYER * 9 * 16384 + 255) / 256, 256, 0, stream>>>(rel_w, root_w, WT);

    // 3 fused RGCN layers
    const int mblocks = (N_NODES + BM - 1) / BM;
    k_layer<<<mblocks, 256, 0, stream>>>(xa, xb, rowptr, edges, WT + 0 * 9 * 16384, bias + 0 * 128);
    k_layer<<<mblocks, 256, 0, stream>>>(xb, xa, rowptr, edges, WT + 1 * 9 * 16384, bias + 1 * 128);
    k_layer<<<mblocks, 256, 0, stream>>>(xa, xb, rowptr, edges, WT + 2 * 9 * 16384, bias + 2 * 128);

    // pool + heads
    k_pool<<<(N_NODES + 2047) / 2048, 256, 0, stream>>>(xb, batch, gsum, gcnt);
    k_heads<<<64, 128, 0, stream>>>(gsum, gcnt, rw1, rb1, rw2, rb2,
                                    sw1, sb1, sw2, sb2, out);
}

// Round 4
// 1705.772 us; speedup vs baseline: 1.2528x; 1.2441x over previous
//
#include <hip/hip_runtime.h>
#include <hip/hip_bf16.h>

#define N_NODES 100000
#define N_EDGES 600000
#define DIM     128
#define N_REL   8
#define N_GRAPH 64
#define N_LAYER 3
#define NR      (N_NODES * N_REL)   // 800000
#define NB1     782                 // ceil(NR / 1024)
#define NP      100032              // N padded to 64-row multiple (A plane stride)

typedef __attribute__((ext_vector_type(8))) short short8;
typedef __attribute__((ext_vector_type(4))) float float4v;

__device__ __forceinline__ float bflo(unsigned int u) {
    return __builtin_bit_cast(float, u << 16);
}
__device__ __forceinline__ float bfhi(unsigned int u) {
    return __builtin_bit_cast(float, u & 0xffff0000u);
}
__device__ __forceinline__ unsigned short f2bf(float f) {
    unsigned int u = __builtin_bit_cast(unsigned int, f);
    u += 0x7fffu + ((u >> 16) & 1u);          // RNE
    return (unsigned short)(u >> 16);
}
__device__ __forceinline__ unsigned int pack2(float a, float b) {
    return (unsigned int)f2bf(a) | ((unsigned int)f2bf(b) << 16);
}
// XOR-swizzled granule index: rows of 128 shorts = 16 granules of 16 B.
__device__ __forceinline__ int gswz(int row, int g) {
    return row * 16 + (g ^ (row & 15));
}

// ---------------- utility: zero int buffer ----------------
__global__ void k_zero(int* __restrict__ p, int n) {
    int i = blockIdx.x * 256 + threadIdx.x;
    if (i < n) p[i] = 0;
}

// ---------------- counting sort of edges by seg = dst*8 + rel (dst-major) ----------------
__global__ void k_hist(const int* __restrict__ ei, const int* __restrict__ et,
                       int* __restrict__ counts) {
    int e = blockIdx.x * 256 + threadIdx.x;
    if (e < N_EDGES) {
        int seg = ei[N_EDGES + e] * N_REL + et[e];
        atomicAdd(&counts[seg], 1);
    }
}

__global__ __launch_bounds__(256) void k_scan1(const int* __restrict__ cnts,
                                               int* __restrict__ part,
                                               int* __restrict__ bsum) {
    __shared__ int sh[256];
    int t = threadIdx.x;
    int base = blockIdx.x * 1024 + t * 4;
    int v0 = (base + 0 < NR) ? cnts[base + 0] : 0;
    int v1 = (base + 1 < NR) ? cnts[base + 1] : 0;
    int v2 = (base + 2 < NR) ? cnts[base + 2] : 0;
    int v3 = (base + 3 < NR) ? cnts[base + 3] : 0;
    int tot = v0 + v1 + v2 + v3;
    sh[t] = tot;
    __syncthreads();
    for (int off = 1; off < 256; off <<= 1) {
        int x = (t >= off) ? sh[t - off] : 0;
        __syncthreads();
        sh[t] += x;
        __syncthreads();
    }
    int exc = sh[t] - tot;
    if (base + 0 < NR) part[base + 0] = exc;
    if (base + 1 < NR) part[base + 1] = exc + v0;
    if (base + 2 < NR) part[base + 2] = exc + v0 + v1;
    if (base + 3 < NR) part[base + 3] = exc + v0 + v1 + v2;
    if (t == 255) bsum[blockIdx.x] = sh[t];
}

__global__ __launch_bounds__(1024) void k_scan2(int* __restrict__ bsum, int nb) {
    __shared__ int sh[1024];
    int t = threadIdx.x;
    int v = (t < nb) ? bsum[t] : 0;
    sh[t] = v;
    __syncthreads();
    for (int off = 1; off < 1024; off <<= 1) {
        int x = (t >= off) ? sh[t - off] : 0;
        __syncthreads();
        sh[t] += x;
        __syncthreads();
    }
    if (t < nb) bsum[t] = sh[t] - v;   // exclusive block offsets
}

__global__ void k_scan3(const int* __restrict__ part, const int* __restrict__ bsum,
                        int* __restrict__ rowptr, int* __restrict__ cursor) {
    int i = blockIdx.x * 256 + threadIdx.x;
    if (i < NR) {
        int v = part[i] + bsum[i >> 10];
        rowptr[i] = v;
        cursor[i] = v;
    }
    if (i == 0) rowptr[NR] = N_EDGES;
}

__global__ void k_scatter(const int* __restrict__ ei, const int* __restrict__ et,
                          int* __restrict__ cursor, int* __restrict__ srcs) {
    int e = blockIdx.x * 256 + threadIdx.x;
    if (e < N_EDGES) {
        int seg = ei[N_EDGES + e] * N_REL + et[e];
        int p = atomicAdd(&cursor[seg], 1);
        srcs[p] = ei[e];
    }
}

// ---------------- x0 = node_emb[node_type], stored bf16x2 ----------------
__global__ void k_gather(const int* __restrict__ nt, const float* __restrict__ emb,
                         unsigned int* __restrict__ x2) {
    int gid = blockIdx.x * 256 + threadIdx.x;
    if (gid < N_NODES * 64) {
        int n = gid >> 6, c2 = gid & 63;
        const float* row = emb + (size_t)nt[n] * DIM + c2 * 2;
        x2[gid] = pack2(row[0], row[1]);
    }
}

// ---------------- weight prep: WT[l][chunk][n][k] bf16 (transposed) ----------------
__global__ void k_wprep(const float* __restrict__ relw, const float* __restrict__ rootw,
                        unsigned short* __restrict__ WT) {
    int gid = blockIdx.x * 256 + threadIdx.x;
    if (gid < N_LAYER * 9 * 16384) {
        int l = gid / (9 * 16384);
        int rem = gid - l * 9 * 16384;
        int c = rem >> 14;
        int idx = rem & 16383;
        int n = idx >> 7, k = idx & 127;
        float w = (c < 8) ? relw[(((size_t)l * 8 + c) * 128 + k) * 128 + n]
                          : rootw[((size_t)l * 128 + k) * 128 + n];
        WT[gid] = f2bf(w);
    }
}

// ---------------- NEW: per-dst aggregation, one wave per node ----------------
// A[r][d][:] = mean over edges (dst=d, rel=r) of xin[src], bf16. No barriers.
#define PF 16
__global__ __launch_bounds__(256) void k_agg(
    const unsigned int* __restrict__ xin,   // [N][64] bf16x2
    const int* __restrict__ rowptr,         // [NR+1], seg = dst*8 + rel
    const int* __restrict__ srcs,           // [E] sorted by seg
    unsigned int* __restrict__ Ag)          // [8][NP][64] bf16x2
{
    __shared__ unsigned int eshm[4 * PF * 64];   // 16 KB: per-wave prefetch buffer
    const int t = threadIdx.x;
    const int wv = t >> 6, lane = t & 63;
    const int d = blockIdx.x * 4 + wv;
    if (d >= N_NODES) return;
    const int wvoff = wv * PF * 64;

    // rowptr[d*8 .. d*8+8] via lane-parallel load + shfl
    int pr = 0;
    if (lane < 9) pr = rowptr[d * 8 + lane];
    const int p0 = __shfl(pr, 0);
    const int deg = __shfl(pr, 8) - p0;

    // all of this node's edge srcs (lane j holds srcs[p0+j], j<64)
    int my_src = 0;
    if (lane < deg) my_src = srcs[p0 + lane];

    // prefetch first PF gathered rows into LDS (burst of independent loads)
#pragma unroll
    for (int q = 0; q < PF; ++q) {
        if (q < deg) {
            int s = __shfl(my_src, q);
            eshm[wvoff + q * 64 + lane] = xin[(size_t)s * 64 + lane];
        }
    }

    // walk relation segments in order
#pragma unroll
    for (int r = 0; r < 8; ++r) {
        int e0 = __shfl(pr, r) - p0;
        int e1 = __shfl(pr, r + 1) - p0;
        int cnt = e1 - e0;
        float a0 = 0.f, a1 = 0.f;
        for (int k = e0; k < e1; ++k) {          // wave-uniform loop
            unsigned int v;
            if (k < PF) {
                v = eshm[wvoff + k * 64 + lane];
            } else {
                int s = (k < 64) ? __shfl(my_src, k) : srcs[p0 + k];
                v = xin[(size_t)s * 64 + lane];
            }
            a0 += bflo(v);
            a1 += bfhi(v);
        }
        float inv = (cnt > 0) ? 1.0f / (float)cnt : 0.f;
        Ag[((size_t)r * NP + d) * 64 + lane] = pack2(a0 * inv, a1 * inv);
    }
}

// ---------------- NEW: dense MFMA GEMM over 9 K-chunks ----------------
// out[m,:] = relu( sum_{c<8} A_c[m,:]@W_c + xin[m,:]@W_root + bias )
#define BM 64
__global__ __launch_bounds__(256) void k_gemm(
    const unsigned int* __restrict__ Ag,    // [8][NP][64] bf16x2
    const unsigned int* __restrict__ xin,   // [N][64] bf16x2 (root chunk)
    unsigned int* __restrict__ xout,        // [N][64] bf16x2
    const unsigned short* __restrict__ WT,  // [9][128(n)][128(k)] bf16
    const float* __restrict__ bias)         // [128]
{
    __shared__ __align__(16) uint4 AslV[64 * 16];    // 16 KB swizzled
    __shared__ __align__(16) uint4 BslV[128 * 16];   // 32 KB swizzled
    const int t = threadIdx.x;
    const int wv = t >> 6, lane = t & 63;
    const int quad = lane >> 4, l15 = lane & 15;
    const int m0 = blockIdx.x * BM;

    const unsigned short* Abfs = (const unsigned short*)AslV;
    const unsigned short* Bbfs = (const unsigned short*)BslV;

    float4v acc[8];
#pragma unroll
    for (int nt = 0; nt < 8; ++nt) {
        float bc = bias[nt * 16 + l15];
        acc[nt] = (float4v){bc, bc, bc, bc};
    }

    for (int c = 0; c < 9; ++c) {
        __syncthreads();
        {
            const uint4* Wc = (const uint4*)(WT + c * 16384);
#pragma unroll
            for (int i = 0; i < 8; ++i) {
                int idx = t + 256 * i;
                BslV[gswz(idx >> 4, idx & 15)] = Wc[idx];
            }
        }
        {
            const uint4* Ac = (c < 8)
                ? (const uint4*)(Ag + ((size_t)c * NP + m0) * 64)
                : (const uint4*)(xin + (size_t)m0 * 64);   // root; tail over-read stays in ws
#pragma unroll
            for (int i = 0; i < 4; ++i) {
                int idx = t + 256 * i;
                AslV[gswz(idx >> 4, idx & 15)] = Ac[idx];
            }
        }
        __syncthreads();
#pragma unroll
        for (int kk = 0; kk < 4; ++kk) {
            int g = kk * 4 + quad;
            short8 a = *(const short8*)(Abfs + gswz(wv * 16 + l15, g) * 8);
#pragma unroll
            for (int nt = 0; nt < 8; ++nt) {
                short8 b = *(const short8*)(Bbfs + gswz(nt * 16 + l15, g) * 8);
                acc[nt] = __builtin_amdgcn_mfma_f32_16x16x32_bf16(a, b, acc[nt], 0, 0, 0);
            }
        }
    }
    // epilogue: relu, store bf16
    unsigned short* outs = (unsigned short*)xout;
#pragma unroll
    for (int nt = 0; nt < 8; ++nt) {
        int colg = nt * 16 + l15;
#pragma unroll
        for (int i = 0; i < 4; ++i) {
            int row = m0 + wv * 16 + quad * 4 + i;
            if (row < N_NODES) {
                float v = acc[nt][i];
                v = v > 0.f ? v : 0.f;
                outs[(size_t)row * 128 + colg] = f2bf(v);
            }
        }
    }
}

// ---------------- FALLBACK (round-1 fused layer; used only if ws too small) ----------------
__global__ __launch_bounds__(256) void k_layer_fb(
    const unsigned int* __restrict__ xin, unsigned int* __restrict__ xout,
    const int* __restrict__ rowptr, const int* __restrict__ srcs,
    const unsigned short* __restrict__ WT, const float* __restrict__ bias)
{
    __shared__ __align__(16) unsigned int Als[BM * 68];
    __shared__ __align__(16) unsigned int Bls[128 * 68];
    const int t = threadIdx.x;
    const int wv = t >> 6, lane = t & 63;
    const int quad = lane >> 4, l15 = lane & 15;
    const int m0 = blockIdx.x * BM;
    const int col2 = t & 63;
    const int rq = t >> 6;

    float4v acc[8];
#pragma unroll
    for (int nt = 0; nt < 8; ++nt) {
        float bc = bias[nt * 16 + l15];
        acc[nt] = (float4v){bc, bc, bc, bc};
    }
    for (int c = 0; c < 9; ++c) {
        if (c < 8) {
            for (int i = 0; i < 16; ++i) {
                int ml = rq + 4 * i;
                int m = m0 + ml;
                float a0 = 0.f, a1 = 0.f, inv = 0.f;
                if (m < N_NODES) {
                    int seg = m * N_REL + c;
                    int s = rowptr[seg], e = rowptr[seg + 1];
                    if (e > s) inv = 1.0f / (float)(e - s);
                    for (int j = s; j < e; ++j) {
                        unsigned int u = xin[(size_t)srcs[j] * 64 + col2];
                        a0 += bflo(u);
                        a1 += bfhi(u);
                    }
                }
                Als[ml * 68 + col2] = pack2(a0 * inv, a1 * inv);
            }
        } else {
            for (int i = 0; i < 16; ++i) {
                int ml = rq + 4 * i;
                int m = m0 + ml;
                Als[ml * 68 + col2] = (m < N_NODES) ? xin[(size_t)m * 64 + col2] : 0u;
            }
        }
        {
            const unsigned int* Wc = (const unsigned int*)(WT + c * 16384);
#pragma unroll
            for (int i = 0; i < 32; ++i) {
                int idx = t + 256 * i;
                Bls[(idx >> 6) * 68 + (idx & 63)] = Wc[idx];
            }
        }
        __syncthreads();
        const short* As = (const short*)Als;
        const short* Bs = (const short*)Bls;
#pragma unroll
        for (int kk = 0; kk < 4; ++kk) {
            short8 a = *(const short8*)(As + (wv * 16 + l15) * 136 + kk * 32 + quad * 8);
#pragma unroll
            for (int nt = 0; nt < 8; ++nt) {
                short8 b = *(const short8*)(Bs + (nt * 16 + l15) * 136 + kk * 32 + quad * 8);
                acc[nt] = __builtin_amdgcn_mfma_f32_16x16x32_bf16(a, b, acc[nt], 0, 0, 0);
            }
        }
        __syncthreads();
    }
    unsigned short* outs = (unsigned short*)xout;
#pragma unroll
    for (int nt = 0; nt < 8; ++nt) {
        int colg = nt * 16 + l15;
#pragma unroll
        for (int i = 0; i < 4; ++i) {
            int row = m0 + wv * 16 + quad * 4 + i;
            if (row < N_NODES) {
                float v = acc[nt][i];
                v = v > 0.f ? v : 0.f;
                outs[(size_t)row * 128 + colg] = f2bf(v);
            }
        }
    }
}

// ---------------- global mean pool (batch is sorted) ----------------
__global__ __launch_bounds__(256) void k_pool(const unsigned int* __restrict__ x2,
                                              const int* __restrict__ batch,
                                              float* __restrict__ gsum,
                                              int* __restrict__ gcnt) {
    int wv = threadIdx.x >> 6, lane = threadIdx.x & 63;
    int cid = blockIdx.x * 4 + wv;
    int n0 = cid * 512;
    if (n0 >= N_NODES) return;
    int n1 = n0 + 512;
    if (n1 > N_NODES) n1 = N_NODES;
    float a0 = 0.f, a1 = 0.f;
    int run = 0;
    int cur = batch[n0];
    for (int n = n0; n < n1; ++n) {
        int b = batch[n];
        if (b != cur) {
            atomicAdd(&gsum[cur * 128 + lane * 2], a0);
            atomicAdd(&gsum[cur * 128 + lane * 2 + 1], a1);
            if (lane == 0) atomicAdd(&gcnt[cur], run);
            a0 = a1 = 0.f;
            run = 0;
            cur = b;
        }
        unsigned int u = x2[(size_t)n * 64 + lane];
        a0 += bflo(u);
        a1 += bfhi(u);
        ++run;
    }
    atomicAdd(&gsum[cur * 128 + lane * 2], a0);
    atomicAdd(&gsum[cur * 128 + lane * 2 + 1], a1);
    if (lane == 0) atomicAdd(&gcnt[cur], run);
}

// ---------------- MLP heads (fp32) ----------------
__global__ __launch_bounds__(128) void k_heads(
    const float* __restrict__ gsum, const int* __restrict__ gcnt,
    const float* __restrict__ rw1, const float* __restrict__ rb1,
    const float* __restrict__ rw2, const float* __restrict__ rb2,
    const float* __restrict__ sw1, const float* __restrict__ sb1,
    const float* __restrict__ sw2, const float* __restrict__ sb2,
    float* __restrict__ out) {
    __shared__ float g[128];
    __shared__ float parts[2];
    int b = blockIdx.x, t = threadIdx.x;
    int c = gcnt[b];
    float invc = 1.0f / (float)(c > 0 ? c : 1);
    g[t] = gsum[b * 128 + t] * invc;
    __syncthreads();
    float acc = rb1[t];
    for (int d = 0; d < 128; ++d) acc += g[d] * rw1[d * 128 + t];
    float h = acc > 0.f ? acc : 0.f;
    float p = h * rw2[t];
    for (int o = 32; o > 0; o >>= 1) p += __shfl_down(p, o);
    if ((t & 63) == 0) parts[t >> 6] = p;
    __syncthreads();
    if (t == 0) out[b] = parts[0] + parts[1] + rb2[0];
    __syncthreads();
    acc = sb1[t];
    for (int d = 0; d < 128; ++d) acc += g[d] * sw1[d * 128 + t];
    h = acc > 0.f ? acc : 0.f;
    p = h * sw2[t];
    for (int o = 32; o > 0; o >>= 1) p += __shfl_down(p, o);
    if ((t & 63) == 0) parts[t >> 6] = p;
    __syncthreads();
    if (t == 0) out[64 + b] = parts[0] + parts[1] + sb2[0];
}

extern "C" void kernel_launch(void* const* d_in, const int* in_sizes, int n_in,
                              void* d_out, int out_size, void* d_ws, size_t ws_size,
                              hipStream_t stream) {
    const int*   node_type  = (const int*)d_in[0];
    const int*   edge_index = (const int*)d_in[1];
    const int*   edge_type  = (const int*)d_in[2];
    const int*   batch      = (const int*)d_in[3];
    const float* node_emb   = (const float*)d_in[4];
    const float* rel_w      = (const float*)d_in[5];
    const float* root_w     = (const float*)d_in[6];
    const float* bias       = (const float*)d_in[7];
    const float* rw1        = (const float*)d_in[8];
    const float* rb1        = (const float*)d_in[9];
    const float* rw2        = (const float*)d_in[10];
    const float* rb2        = (const float*)d_in[11];
    const float* sw1        = (const float*)d_in[12];
    const float* sb1        = (const float*)d_in[13];
    const float* sw2        = (const float*)d_in[14];
    const float* sb2        = (const float*)d_in[15];
    float* out = (float*)d_out;

    char* ws = (char*)d_ws;
    size_t off = 0;
    auto alloc = [&](size_t bytes) -> void* {
        void* p = ws + off;
        off += (bytes + 255) & ~(size_t)255;
        return p;
    };
    unsigned int*   xa     = (unsigned int*)alloc((size_t)N_NODES * 64 * 4);
    unsigned int*   xb     = (unsigned int*)alloc((size_t)N_NODES * 64 * 4);
    int*            rowptr = (int*)alloc((size_t)(NR + 1) * 4);
    int*            cursor = (int*)alloc((size_t)NR * 4);
    int*            counts = (int*)alloc((size_t)NR * 4);
    int*            srcs   = (int*)alloc((size_t)N_EDGES * 4);
    int*            bsum   = (int*)alloc(1024 * 4);
    unsigned short* WT     = (unsigned short*)alloc((size_t)N_LAYER * 9 * 16384 * 2);
    float*          gsum   = (float*)alloc((64 * 128 + 64) * 4);
    int*            gcnt   = (int*)(gsum + 64 * 128);
    size_t off_common = off;
    unsigned int*   Ag     = (unsigned int*)alloc((size_t)8 * NP * 64 * 4);  // 204.9 MB
    const bool bigws = (off <= ws_size);
    if (off_common > ws_size) return;  // even fallback can't run

    // edge sort (counting sort by dst*8 + rel)
    k_zero<<<(NR + 255) / 256, 256, 0, stream>>>(counts, NR);
    k_zero<<<(64 * 128 + 64 + 255) / 256, 256, 0, stream>>>((int*)gsum, 64 * 128 + 64);
    k_hist<<<(N_EDGES + 255) / 256, 256, 0, stream>>>(edge_index, edge_type, counts);
    k_scan1<<<NB1, 256, 0, stream>>>(counts, cursor, bsum);
    k_scan2<<<1, 1024, 0, stream>>>(bsum, NB1);
    k_scan3<<<(NR + 255) / 256, 256, 0, stream>>>(cursor, bsum, rowptr, cursor);
    k_scatter<<<(N_EDGES + 255) / 256, 256, 0, stream>>>(edge_index, edge_type, cursor, srcs);

    // x0 gather + weight prep
    k_gather<<<(N_NODES * 64 + 255) / 256, 256, 0, stream>>>(node_type, node_emb, xa);
    k_wprep<<<(N_LAYER * 9 * 16384 + 255) / 256, 256, 0, stream>>>(rel_w, root_w, WT);

    const int mblocks = (N_NODES + BM - 1) / BM;   // 1563
    const int ablocks = (N_NODES + 3) / 4;          // 25000
    unsigned int* xcur = xa;
    unsigned int* xnext = xb;
    for (int l = 0; l < N_LAYER; ++l) {
        const unsigned short* Wl = WT + (size_t)l * 9 * 16384;
        const float* bl = bias + (size_t)l * 128;
        if (bigws) {
            k_agg<<<ablocks, 256, 0, stream>>>(xcur, rowptr, srcs, Ag);
            k_gemm<<<mblocks, 256, 0, stream>>>(Ag, xcur, xnext, Wl, bl);
        } else {
            k_layer_fb<<<mblocks, 256, 0, stream>>>(xcur, xnext, rowptr, srcs, Wl, bl);
        }
        unsigned int* tmp = xcur; xcur = xnext; xnext = tmp;
    }

    // pool + heads (final activations are in xcur after swap)
    k_pool<<<(N_NODES + 2047) / 2048, 256, 0, stream>>>(xcur, batch, gsum, gcnt);
    k_heads<<<64, 128, 0, stream>>>(gsum, gcnt, rw1, rb1, rw2, rb2,
                                    sw1, sb1, sw2, sb2, out);
}

// Round 5
// 798.132 us; speedup vs baseline: 2.6775x; 2.1372x over previous
//
#include <hip/hip_runtime.h>
#include <hip/hip_bf16.h>

#define N_NODES 100000
#define N_EDGES 600000
#define DIM     128
#define N_REL   8
#define N_GRAPH 64
#define N_LAYER 3
#define NR      (N_NODES * N_REL)   // 800000
#define NB1     782                 // ceil(NR / 1024)

typedef __attribute__((ext_vector_type(8))) short short8;
typedef __attribute__((ext_vector_type(4))) float float4v;

__device__ __forceinline__ float bflo(unsigned int u) {
    return __builtin_bit_cast(float, u << 16);
}
__device__ __forceinline__ float bfhi(unsigned int u) {
    return __builtin_bit_cast(float, u & 0xffff0000u);
}
__device__ __forceinline__ unsigned short f2bf(float f) {
    unsigned int u = __builtin_bit_cast(unsigned int, f);
    u += 0x7fffu + ((u >> 16) & 1u);          // RNE
    return (unsigned short)(u >> 16);
}
__device__ __forceinline__ unsigned int pack2(float a, float b) {
    return (unsigned int)f2bf(a) | ((unsigned int)f2bf(b) << 16);
}
// XOR-swizzled granule index: rows of 128 shorts = 16 granules of 16 B.
__device__ __forceinline__ int gswz(int row, int g) {
    return row * 16 + (g ^ (row & 15));
}

// ---------------- utility: zero int buffer ----------------
__global__ void k_zero(int* __restrict__ p, int n) {
    int i = blockIdx.x * 256 + threadIdx.x;
    if (i < n) p[i] = 0;
}

// ---------------- counting sort of edges by seg = dst*8 + rel (dst-major) ----------------
__global__ void k_hist(const int* __restrict__ ei, const int* __restrict__ et,
                       int* __restrict__ counts) {
    int e = blockIdx.x * 256 + threadIdx.x;
    if (e < N_EDGES) {
        int seg = ei[N_EDGES + e] * N_REL + et[e];
        atomicAdd(&counts[seg], 1);
    }
}

__global__ __launch_bounds__(256) void k_scan1(const int* __restrict__ cnts,
                                               int* __restrict__ part,
                                               int* __restrict__ bsum) {
    __shared__ int sh[256];
    int t = threadIdx.x;
    int base = blockIdx.x * 1024 + t * 4;
    int v0 = (base + 0 < NR) ? cnts[base + 0] : 0;
    int v1 = (base + 1 < NR) ? cnts[base + 1] : 0;
    int v2 = (base + 2 < NR) ? cnts[base + 2] : 0;
    int v3 = (base + 3 < NR) ? cnts[base + 3] : 0;
    int tot = v0 + v1 + v2 + v3;
    sh[t] = tot;
    __syncthreads();
    for (int off = 1; off < 256; off <<= 1) {
        int x = (t >= off) ? sh[t - off] : 0;
        __syncthreads();
        sh[t] += x;
        __syncthreads();
    }
    int exc = sh[t] - tot;
    if (base + 0 < NR) part[base + 0] = exc;
    if (base + 1 < NR) part[base + 1] = exc + v0;
    if (base + 2 < NR) part[base + 2] = exc + v0 + v1;
    if (base + 3 < NR) part[base + 3] = exc + v0 + v1 + v2;
    if (t == 255) bsum[blockIdx.x] = sh[t];
}

__global__ __launch_bounds__(1024) void k_scan2(int* __restrict__ bsum, int nb) {
    __shared__ int sh[1024];
    int t = threadIdx.x;
    int v = (t < nb) ? bsum[t] : 0;
    sh[t] = v;
    __syncthreads();
    for (int off = 1; off < 1024; off <<= 1) {
        int x = (t >= off) ? sh[t - off] : 0;
        __syncthreads();
        sh[t] += x;
        __syncthreads();
    }
    if (t < nb) bsum[t] = sh[t] - v;   // exclusive block offsets
}

__global__ void k_scan3(const int* __restrict__ part, const int* __restrict__ bsum,
                        int* __restrict__ rowptr, int* __restrict__ cursor) {
    int i = blockIdx.x * 256 + threadIdx.x;
    if (i < NR) {
        int v = part[i] + bsum[i >> 10];
        rowptr[i] = v;
        cursor[i] = v;
    }
    if (i == 0) rowptr[NR] = N_EDGES;
}

__global__ void k_scatter(const int* __restrict__ ei, const int* __restrict__ et,
                          int* __restrict__ cursor, int* __restrict__ srcs) {
    int e = blockIdx.x * 256 + threadIdx.x;
    if (e < N_EDGES) {
        int seg = ei[N_EDGES + e] * N_REL + et[e];
        int p = atomicAdd(&cursor[seg], 1);
        srcs[p] = ei[e];
    }
}

// ---------------- x0 = node_emb[node_type], stored bf16x2 ----------------
__global__ void k_gather(const int* __restrict__ nt, const float* __restrict__ emb,
                         unsigned int* __restrict__ x2) {
    int gid = blockIdx.x * 256 + threadIdx.x;
    if (gid < N_NODES * 64) {
        int n = gid >> 6, c2 = gid & 63;
        const float* row = emb + (size_t)nt[n] * DIM + c2 * 2;
        x2[gid] = pack2(row[0], row[1]);
    }
}

// ---------------- weight prep: WT[l][chunk][n][k] bf16 (transposed) ----------------
__global__ void k_wprep(const float* __restrict__ relw, const float* __restrict__ rootw,
                        unsigned short* __restrict__ WT) {
    int gid = blockIdx.x * 256 + threadIdx.x;
    if (gid < N_LAYER * 9 * 16384) {
        int l = gid / (9 * 16384);
        int rem = gid - l * 9 * 16384;
        int c = rem >> 14;
        int idx = rem & 16383;
        int n = idx >> 7, k = idx & 127;
        float w = (c < 8) ? relw[(((size_t)l * 8 + c) * 128 + k) * 128 + n]
                          : rootw[((size_t)l * 128 + k) * 128 + n];
        WT[gid] = f2bf(w);
    }
}

// ---------------- per-dst aggregation, one wave per node (sliced) ----------------
// Ag[r][d-d0][:] = mean over edges (dst=d, rel=r) of xin[src], bf16. No barriers.
#define PF 16
__global__ __launch_bounds__(256) void k_agg(
    const unsigned int* __restrict__ xin,   // [N][64] bf16x2
    const int* __restrict__ rowptr,         // [NR+1], seg = dst*8 + rel
    const int* __restrict__ srcs,           // [E] sorted by seg
    unsigned int* __restrict__ Ag,          // [8][srows][64] bf16x2
    int d0, int rows, int srows)
{
    __shared__ unsigned int eshm[4 * PF * 64];   // 16 KB: per-wave prefetch buffer
    const int t = threadIdx.x;
    const int wv = t >> 6, lane = t & 63;
    const int dl = blockIdx.x * 4 + wv;
    if (dl >= rows) return;
    const int d = d0 + dl;
    const int wvoff = wv * PF * 64;

    // rowptr[d*8 .. d*8+8] via lane-parallel load + shfl
    int pr = 0;
    if (lane < 9) pr = rowptr[d * 8 + lane];
    const int p0 = __shfl(pr, 0);
    const int deg = __shfl(pr, 8) - p0;

    // lane j holds srcs[p0+j] (first 64 edges of this node)
    int my_src = 0;
    if (lane < deg) my_src = srcs[p0 + lane];

    // prefetch first PF gathered rows into LDS (burst of independent loads)
#pragma unroll
    for (int q = 0; q < PF; ++q) {
        if (q < deg) {
            int s = __shfl(my_src, q);
            eshm[wvoff + q * 64 + lane] = xin[(size_t)s * 64 + lane];
        }
    }

    // walk relation segments in order
#pragma unroll
    for (int r = 0; r < 8; ++r) {
        int e0 = __shfl(pr, r) - p0;
        int e1 = __shfl(pr, r + 1) - p0;
        int cnt = e1 - e0;
        float a0 = 0.f, a1 = 0.f;
        for (int k = e0; k < e1; ++k) {          // wave-uniform loop
            unsigned int v;
            if (k < PF) {
                v = eshm[wvoff + k * 64 + lane];
            } else {
                int s = (k < 64) ? __shfl(my_src, k) : srcs[p0 + k];
                v = xin[(size_t)s * 64 + lane];
            }
            a0 += bflo(v);
            a1 += bfhi(v);
        }
        float inv = (cnt > 0) ? 1.0f / (float)cnt : 0.f;
        Ag[((size_t)r * srows + dl) * 64 + lane] = pack2(a0 * inv, a1 * inv);
    }
}

// ---------------- dense MFMA GEMM over 9 K-chunks (sliced) ----------------
// out[m,:] = relu( sum_{c<8} A_c[m,:]@W_c + xin[m,:]@W_root + bias )
#define BM 64
__global__ __launch_bounds__(256) void k_gemm(
    const unsigned int* __restrict__ Ag,    // [8][srows][64] bf16x2
    const unsigned int* __restrict__ xin,   // [N][64] bf16x2 (root chunk)
    unsigned int* __restrict__ xout,        // [N][64] bf16x2
    const unsigned short* __restrict__ WT,  // [9][128(n)][128(k)] bf16
    const float* __restrict__ bias,         // [128]
    int d0, int srows)
{
    __shared__ __align__(16) uint4 AslV[64 * 16];    // 16 KB swizzled
    __shared__ __align__(16) uint4 BslV[128 * 16];   // 32 KB swizzled
    const int t = threadIdx.x;
    const int wv = t >> 6, lane = t & 63;
    const int quad = lane >> 4, l15 = lane & 15;
    const int m0 = d0 + blockIdx.x * BM;

    const unsigned short* Abfs = (const unsigned short*)AslV;
    const unsigned short* Bbfs = (const unsigned short*)BslV;

    float4v acc[8];
#pragma unroll
    for (int nt = 0; nt < 8; ++nt) {
        float bc = bias[nt * 16 + l15];
        acc[nt] = (float4v){bc, bc, bc, bc};
    }

    for (int c = 0; c < 9; ++c) {
        __syncthreads();
        {
            const uint4* Wc = (const uint4*)(WT + c * 16384);
#pragma unroll
            for (int i = 0; i < 8; ++i) {
                int idx = t + 256 * i;
                BslV[gswz(idx >> 4, idx & 15)] = Wc[idx];
            }
        }
        {
            const uint4* Ac = (c < 8)
                ? (const uint4*)(Ag + ((size_t)c * srows + (m0 - d0)) * 64)
                : (const uint4*)(xin + (size_t)m0 * 64);   // root; tail over-read stays in ws
#pragma unroll
            for (int i = 0; i < 4; ++i) {
                int idx = t + 256 * i;
                AslV[gswz(idx >> 4, idx & 15)] = Ac[idx];
            }
        }
        __syncthreads();
#pragma unroll
        for (int kk = 0; kk < 4; ++kk) {
            int g = kk * 4 + quad;
            short8 a = *(const short8*)(Abfs + gswz(wv * 16 + l15, g) * 8);
#pragma unroll
            for (int nt = 0; nt < 8; ++nt) {
                short8 b = *(const short8*)(Bbfs + gswz(nt * 16 + l15, g) * 8);
                acc[nt] = __builtin_amdgcn_mfma_f32_16x16x32_bf16(a, b, acc[nt], 0, 0, 0);
            }
        }
    }
    // epilogue: relu, store bf16
    unsigned short* outs = (unsigned short*)xout;
#pragma unroll
    for (int nt = 0; nt < 8; ++nt) {
        int colg = nt * 16 + l15;
#pragma unroll
        for (int i = 0; i < 4; ++i) {
            int row = m0 + wv * 16 + quad * 4 + i;
            if (row < N_NODES) {
                float v = acc[nt][i];
                v = v > 0.f ? v : 0.f;
                outs[(size_t)row * 128 + colg] = f2bf(v);
            }
        }
    }
}

// ---------------- FALLBACK (round-1 fused layer; used only if ws too small) ----------------
__global__ __launch_bounds__(256) void k_layer_fb(
    const unsigned int* __restrict__ xin, unsigned int* __restrict__ xout,
    const int* __restrict__ rowptr, const int* __restrict__ srcs,
    const unsigned short* __restrict__ WT, const float* __restrict__ bias)
{
    __shared__ __align__(16) unsigned int Als[BM * 68];
    __shared__ __align__(16) unsigned int Bls[128 * 68];
    const int t = threadIdx.x;
    const int wv = t >> 6, lane = t & 63;
    const int quad = lane >> 4, l15 = lane & 15;
    const int m0 = blockIdx.x * BM;
    const int col2 = t & 63;
    const int rq = t >> 6;

    float4v acc[8];
#pragma unroll
    for (int nt = 0; nt < 8; ++nt) {
        float bc = bias[nt * 16 + l15];
        acc[nt] = (float4v){bc, bc, bc, bc};
    }
    for (int c = 0; c < 9; ++c) {
        if (c < 8) {
            for (int i = 0; i < 16; ++i) {
                int ml = rq + 4 * i;
                int m = m0 + ml;
                float a0 = 0.f, a1 = 0.f, inv = 0.f;
                if (m < N_NODES) {
                    int seg = m * N_REL + c;
                    int s = rowptr[seg], e = rowptr[seg + 1];
                    if (e > s) inv = 1.0f / (float)(e - s);
                    for (int j = s; j < e; ++j) {
                        unsigned int u = xin[(size_t)srcs[j] * 64 + col2];
                        a0 += bflo(u);
                        a1 += bfhi(u);
                    }
                }
                Als[ml * 68 + col2] = pack2(a0 * inv, a1 * inv);
            }
        } else {
            for (int i = 0; i < 16; ++i) {
                int ml = rq + 4 * i;
                int m = m0 + ml;
                Als[ml * 68 + col2] = (m < N_NODES) ? xin[(size_t)m * 64 + col2] : 0u;
            }
        }
        {
            const unsigned int* Wc = (const unsigned int*)(WT + c * 16384);
#pragma unroll
            for (int i = 0; i < 32; ++i) {
                int idx = t + 256 * i;
                Bls[(idx >> 6) * 68 + (idx & 63)] = Wc[idx];
            }
        }
        __syncthreads();
        const short* As = (const short*)Als;
        const short* Bs = (const short*)Bls;
#pragma unroll
        for (int kk = 0; kk < 4; ++kk) {
            short8 a = *(const short8*)(As + (wv * 16 + l15) * 136 + kk * 32 + quad * 8);
#pragma unroll
            for (int nt = 0; nt < 8; ++nt) {
                short8 b = *(const short8*)(Bs + (nt * 16 + l15) * 136 + kk * 32 + quad * 8);
                acc[nt] = __builtin_amdgcn_mfma_f32_16x16x32_bf16(a, b, acc[nt], 0, 0, 0);
            }
        }
        __syncthreads();
    }
    unsigned short* outs = (unsigned short*)xout;
#pragma unroll
    for (int nt = 0; nt < 8; ++nt) {
        int colg = nt * 16 + l15;
#pragma unroll
        for (int i = 0; i < 4; ++i) {
            int row = m0 + wv * 16 + quad * 4 + i;
            if (row < N_NODES) {
                float v = acc[nt][i];
                v = v > 0.f ? v : 0.f;
                outs[(size_t)row * 128 + colg] = f2bf(v);
            }
        }
    }
}

// ---------------- global mean pool (batch is sorted) ----------------
__global__ __launch_bounds__(256) void k_pool(const unsigned int* __restrict__ x2,
                                              const int* __restrict__ batch,
                                              float* __restrict__ gsum,
                                              int* __restrict__ gcnt) {
    int wv = threadIdx.x >> 6, lane = threadIdx.x & 63;
    int cid = blockIdx.x * 4 + wv;
    int n0 = cid * 512;
    if (n0 >= N_NODES) return;
    int n1 = n0 + 512;
    if (n1 > N_NODES) n1 = N_NODES;
    float a0 = 0.f, a1 = 0.f;
    int run = 0;
    int cur = batch[n0];
    for (int n = n0; n < n1; ++n) {
        int b = batch[n];
        if (b != cur) {
            atomicAdd(&gsum[cur * 128 + lane * 2], a0);
            atomicAdd(&gsum[cur * 128 + lane * 2 + 1], a1);
            if (lane == 0) atomicAdd(&gcnt[cur], run);
            a0 = a1 = 0.f;
            run = 0;
            cur = b;
        }
        unsigned int u = x2[(size_t)n * 64 + lane];
        a0 += bflo(u);
        a1 += bfhi(u);
        ++run;
    }
    atomicAdd(&gsum[cur * 128 + lane * 2], a0);
    atomicAdd(&gsum[cur * 128 + lane * 2 + 1], a1);
    if (lane == 0) atomicAdd(&gcnt[cur], run);
}

// ---------------- MLP heads (fp32) ----------------
__global__ __launch_bounds__(128) void k_heads(
    const float* __restrict__ gsum, const int* __restrict__ gcnt,
    const float* __restrict__ rw1, const float* __restrict__ rb1,
    const float* __restrict__ rw2, const float* __restrict__ rb2,
    const float* __restrict__ sw1, const float* __restrict__ sb1,
    const float* __restrict__ sw2, const float* __restrict__ sb2,
    float* __restrict__ out) {
    __shared__ float g[128];
    __shared__ float parts[2];
    int b = blockIdx.x, t = threadIdx.x;
    int c = gcnt[b];
    float invc = 1.0f / (float)(c > 0 ? c : 1);
    g[t] = gsum[b * 128 + t] * invc;
    __syncthreads();
    float acc = rb1[t];
    for (int d = 0; d < 128; ++d) acc += g[d] * rw1[d * 128 + t];
    float h = acc > 0.f ? acc : 0.f;
    float p = h * rw2[t];
    for (int o = 32; o > 0; o >>= 1) p += __shfl_down(p, o);
    if ((t & 63) == 0) parts[t >> 6] = p;
    __syncthreads();
    if (t == 0) out[b] = parts[0] + parts[1] + rb2[0];
    __syncthreads();
    acc = sb1[t];
    for (int d = 0; d < 128; ++d) acc += g[d] * sw1[d * 128 + t];
    h = acc > 0.f ? acc : 0.f;
    p = h * sw2[t];
    for (int o = 32; o > 0; o >>= 1) p += __shfl_down(p, o);
    if ((t & 63) == 0) parts[t >> 6] = p;
    __syncthreads();
    if (t == 0) out[64 + b] = parts[0] + parts[1] + sb2[0];
}

extern "C" void kernel_launch(void* const* d_in, const int* in_sizes, int n_in,
                              void* d_out, int out_size, void* d_ws, size_t ws_size,
                              hipStream_t stream) {
    const int*   node_type  = (const int*)d_in[0];
    const int*   edge_index = (const int*)d_in[1];
    const int*   edge_type  = (const int*)d_in[2];
    const int*   batch      = (const int*)d_in[3];
    const float* node_emb   = (const float*)d_in[4];
    const float* rel_w      = (const float*)d_in[5];
    const float* root_w     = (const float*)d_in[6];
    const float* bias       = (const float*)d_in[7];
    const float* rw1        = (const float*)d_in[8];
    const float* rb1        = (const float*)d_in[9];
    const float* rw2        = (const float*)d_in[10];
    const float* rb2        = (const float*)d_in[11];
    const float* sw1        = (const float*)d_in[12];
    const float* sb1        = (const float*)d_in[13];
    const float* sw2        = (const float*)d_in[14];
    const float* sb2        = (const float*)d_in[15];
    float* out = (float*)d_out;

    char* ws = (char*)d_ws;
    size_t off = 0;
    auto alloc = [&](size_t bytes) -> void* {
        void* p = ws + off;
        off += (bytes + 255) & ~(size_t)255;
        return p;
    };
    // ---- persistent region ----
    unsigned int*   xa     = (unsigned int*)alloc((size_t)N_NODES * 64 * 4);
    unsigned int*   xb     = (unsigned int*)alloc((size_t)N_NODES * 64 * 4);
    int*            rowptr = (int*)alloc((size_t)(NR + 1) * 4);
    int*            srcs   = (int*)alloc((size_t)N_EDGES * 4);
    int*            bsum   = (int*)alloc(1024 * 4);
    unsigned short* WT     = (unsigned short*)alloc((size_t)N_LAYER * 9 * 16384 * 2);
    float*          gsum   = (float*)alloc((64 * 128 + 64) * 4);
    int*            gcnt   = (int*)(gsum + 64 * 128);
    size_t off_common = off;
    // ---- scratch region: sort temps, later overlapped by Ag slices ----
    int*            cursor = (int*)alloc((size_t)NR * 4);
    int*            counts = (int*)alloc((size_t)NR * 4);
    size_t off_sort = off;
    if (off_sort > ws_size) return;                // cannot run at all
    unsigned int*   Ag     = (unsigned int*)(ws + off_common);  // overlaps cursor/counts
    size_t avail = ws_size - off_common;
    long max_rows = (long)(avail / 2048);          // bytes per node-row: 8 planes * 256 B
    int srows = (int)((max_rows / 64) * 64);
    if (srows > N_NODES + 63) srows = ((N_NODES + 63) / 64) * 64;
    const bool split_ok = (srows >= 64);

    // edge sort (counting sort by dst*8 + rel)
    k_zero<<<(NR + 255) / 256, 256, 0, stream>>>(counts, NR);
    k_zero<<<(64 * 128 + 64 + 255) / 256, 256, 0, stream>>>((int*)gsum, 64 * 128 + 64);
    k_hist<<<(N_EDGES + 255) / 256, 256, 0, stream>>>(edge_index, edge_type, counts);
    k_scan1<<<NB1, 256, 0, stream>>>(counts, cursor, bsum);
    k_scan2<<<1, 1024, 0, stream>>>(bsum, NB1);
    k_scan3<<<(NR + 255) / 256, 256, 0, stream>>>(cursor, bsum, rowptr, cursor);
    k_scatter<<<(N_EDGES + 255) / 256, 256, 0, stream>>>(edge_index, edge_type, cursor, srcs);

    // x0 gather + weight prep
    k_gather<<<(N_NODES * 64 + 255) / 256, 256, 0, stream>>>(node_type, node_emb, xa);
    k_wprep<<<(N_LAYER * 9 * 16384 + 255) / 256, 256, 0, stream>>>(rel_w, root_w, WT);

    const int mblocks = (N_NODES + BM - 1) / BM;   // 1563
    unsigned int* xcur = xa;
    unsigned int* xnext = xb;
    for (int l = 0; l < N_LAYER; ++l) {
        const unsigned short* Wl = WT + (size_t)l * 9 * 16384;
        const float* bl = bias + (size_t)l * 128;
        if (split_ok) {
            for (int d0 = 0; d0 < N_NODES; d0 += srows) {
                int rows = N_NODES - d0;
                if (rows > srows) rows = srows;
                int ab = (rows + 3) / 4;
                int gb = (rows + BM - 1) / BM;
                k_agg<<<ab, 256, 0, stream>>>(xcur, rowptr, srcs, Ag, d0, rows, srows);
                k_gemm<<<gb, 256, 0, stream>>>(Ag, xcur, xnext, Wl, bl, d0, srows);
            }
        } else {
            k_layer_fb<<<mblocks, 256, 0, stream>>>(xcur, xnext, rowptr, srcs, Wl, bl);
        }
        unsigned int* tmp = xcur; xcur = xnext; xnext = tmp;
    }

    // pool + heads (final activations are in xcur after swap)
    k_pool<<<(N_NODES + 2047) / 2048, 256, 0, stream>>>(xcur, batch, gsum, gcnt);
    k_heads<<<64, 128, 0, stream>>>(gsum, gcnt, rw1, rb1, rw2, rb2,
                                    sw1, sb1, sw2, sb2, out);
}

// Round 6
// 628.800 us; speedup vs baseline: 3.3985x; 1.2693x over previous
//
#include <hip/hip_runtime.h>
#include <hip/hip_bf16.h>

#define N_NODES 100000
#define N_EDGES 600000
#define DIM     128
#define N_REL   8
#define N_GRAPH 64
#define N_LAYER 3
#define NR      (N_NODES * N_REL)   // 800000
#define NB1     782                 // ceil(NR / 1024)

typedef __attribute__((ext_vector_type(8))) short short8;
typedef __attribute__((ext_vector_type(4))) float float4v;

__device__ __forceinline__ float bflo(unsigned int u) {
    return __builtin_bit_cast(float, u << 16);
}
__device__ __forceinline__ float bfhi(unsigned int u) {
    return __builtin_bit_cast(float, u & 0xffff0000u);
}
__device__ __forceinline__ unsigned short f2bf(float f) {
    unsigned int u = __builtin_bit_cast(unsigned int, f);
    u += 0x7fffu + ((u >> 16) & 1u);          // RNE
    return (unsigned short)(u >> 16);
}
__device__ __forceinline__ unsigned int pack2(float a, float b) {
    return (unsigned int)f2bf(a) | ((unsigned int)f2bf(b) << 16);
}
// XOR-swizzled granule index: rows of 128 shorts = 16 granules of 16 B.
__device__ __forceinline__ int gswz(int row, int g) {
    return row * 16 + (g ^ (row & 15));
}

// ---------------- utility: zero int buffer ----------------
__global__ void k_zero(int* __restrict__ p, int n) {
    int i = blockIdx.x * 256 + threadIdx.x;
    if (i < n) p[i] = 0;
}

// ---------------- counting sort of edges by seg = dst*8 + rel (dst-major) ----------------
__global__ void k_hist(const int* __restrict__ ei, const int* __restrict__ et,
                       int* __restrict__ counts) {
    int e = blockIdx.x * 256 + threadIdx.x;
    if (e < N_EDGES) {
        int seg = ei[N_EDGES + e] * N_REL + et[e];
        atomicAdd(&counts[seg], 1);
    }
}

__global__ __launch_bounds__(256) void k_scan1(const int* __restrict__ cnts,
                                               int* __restrict__ part,
                                               int* __restrict__ bsum) {
    __shared__ int sh[256];
    int t = threadIdx.x;
    int base = blockIdx.x * 1024 + t * 4;
    int v0 = (base + 0 < NR) ? cnts[base + 0] : 0;
    int v1 = (base + 1 < NR) ? cnts[base + 1] : 0;
    int v2 = (base + 2 < NR) ? cnts[base + 2] : 0;
    int v3 = (base + 3 < NR) ? cnts[base + 3] : 0;
    int tot = v0 + v1 + v2 + v3;
    sh[t] = tot;
    __syncthreads();
    for (int off = 1; off < 256; off <<= 1) {
        int x = (t >= off) ? sh[t - off] : 0;
        __syncthreads();
        sh[t] += x;
        __syncthreads();
    }
    int exc = sh[t] - tot;
    if (base + 0 < NR) part[base + 0] = exc;
    if (base + 1 < NR) part[base + 1] = exc + v0;
    if (base + 2 < NR) part[base + 2] = exc + v0 + v1;
    if (base + 3 < NR) part[base + 3] = exc + v0 + v1 + v2;
    if (t == 255) bsum[blockIdx.x] = sh[t];
}

__global__ __launch_bounds__(1024) void k_scan2(int* __restrict__ bsum, int nb) {
    __shared__ int sh[1024];
    int t = threadIdx.x;
    int v = (t < nb) ? bsum[t] : 0;
    sh[t] = v;
    __syncthreads();
    for (int off = 1; off < 1024; off <<= 1) {
        int x = (t >= off) ? sh[t - off] : 0;
        __syncthreads();
        sh[t] += x;
        __syncthreads();
    }
    if (t < nb) bsum[t] = sh[t] - v;   // exclusive block offsets
}

__global__ void k_scan3(const int* __restrict__ part, const int* __restrict__ bsum,
                        int* __restrict__ rowptr, int* __restrict__ cursor) {
    int i = blockIdx.x * 256 + threadIdx.x;
    if (i < NR) {
        int v = part[i] + bsum[i >> 10];
        rowptr[i] = v;
        cursor[i] = v;
    }
    if (i == 0) rowptr[NR] = N_EDGES;
}

__global__ void k_scatter(const int* __restrict__ ei, const int* __restrict__ et,
                          int* __restrict__ cursor, int* __restrict__ srcs) {
    int e = blockIdx.x * 256 + threadIdx.x;
    if (e < N_EDGES) {
        int seg = ei[N_EDGES + e] * N_REL + et[e];
        int p = atomicAdd(&cursor[seg], 1);
        srcs[p] = ei[e];
    }
}

// ---------------- x0 = node_emb[node_type], stored bf16x2 ----------------
__global__ void k_gather(const int* __restrict__ nt, const float* __restrict__ emb,
                         unsigned int* __restrict__ x2) {
    int gid = blockIdx.x * 256 + threadIdx.x;
    if (gid < N_NODES * 64) {
        int n = gid >> 6, c2 = gid & 63;
        const float* row = emb + (size_t)nt[n] * DIM + c2 * 2;
        x2[gid] = pack2(row[0], row[1]);
    }
}

// ---------------- weight prep: WT[l][chunk][n][k] bf16 (transposed) ----------------
__global__ void k_wprep(const float* __restrict__ relw, const float* __restrict__ rootw,
                        unsigned short* __restrict__ WT) {
    int gid = blockIdx.x * 256 + threadIdx.x;
    if (gid < N_LAYER * 9 * 16384) {
        int l = gid / (9 * 16384);
        int rem = gid - l * 9 * 16384;
        int c = rem >> 14;
        int idx = rem & 16383;
        int n = idx >> 7, k = idx & 127;
        float w = (c < 8) ? relw[(((size_t)l * 8 + c) * 128 + k) * 128 + n]
                          : rootw[((size_t)l * 128 + k) * 128 + n];
        WT[gid] = f2bf(w);
    }
}

// ---------------- per-dst aggregation, one wave per node (sliced) ----------------
// Ag[r][d-d0][:] = mean over edges (dst=d, rel=r) of xin[src], bf16. No barriers.
#define PF 16
__global__ __launch_bounds__(256) void k_agg(
    const unsigned int* __restrict__ xin,   // [N][64] bf16x2
    const int* __restrict__ rowptr,         // [NR+1], seg = dst*8 + rel
    const int* __restrict__ srcs,           // [E] sorted by seg
    unsigned int* __restrict__ Ag,          // [8][srows][64] bf16x2
    int d0, int rows, int srows)
{
    __shared__ unsigned int eshm[4 * PF * 64];   // 16 KB: per-wave prefetch buffer
    const int t = threadIdx.x;
    const int wv = t >> 6, lane = t & 63;
    const int dl = blockIdx.x * 4 + wv;
    if (dl >= rows) return;
    const int d = d0 + dl;
    const int wvoff = wv * PF * 64;

    // rowptr[d*8 .. d*8+8] via lane-parallel load + shfl
    int pr = 0;
    if (lane < 9) pr = rowptr[d * 8 + lane];
    const int p0 = __shfl(pr, 0);
    const int deg = __shfl(pr, 8) - p0;

    // lane j holds srcs[p0+j] (first 64 edges of this node)
    int my_src = 0;
    if (lane < deg) my_src = srcs[p0 + lane];

    // prefetch first PF gathered rows into LDS (burst of independent loads)
#pragma unroll
    for (int q = 0; q < PF; ++q) {
        if (q < deg) {
            int s = __shfl(my_src, q);
            eshm[wvoff + q * 64 + lane] = xin[(size_t)s * 64 + lane];
        }
    }

    // walk relation segments in order
#pragma unroll
    for (int r = 0; r < 8; ++r) {
        int e0 = __shfl(pr, r) - p0;
        int e1 = __shfl(pr, r + 1) - p0;
        int cnt = e1 - e0;
        float a0 = 0.f, a1 = 0.f;
        for (int k = e0; k < e1; ++k) {          // wave-uniform loop
            unsigned int v;
            if (k < PF) {
                v = eshm[wvoff + k * 64 + lane];
            } else {
                int s = (k < 64) ? __shfl(my_src, k) : srcs[p0 + k];
                v = xin[(size_t)s * 64 + lane];
            }
            a0 += bflo(v);
            a1 += bfhi(v);
        }
        float inv = (cnt > 0) ? 1.0f / (float)cnt : 0.f;
        Ag[((size_t)r * srows + dl) * 64 + lane] = pack2(a0 * inv, a1 * inv);
    }
}

// ---------------- dense MFMA GEMM over 9 K-chunks (sliced) ----------------
// out[m,:] = relu( sum_{c<8} A_c[m,:]@W_c + xin[m,:]@W_root + bias )
#define BM 64
__global__ __launch_bounds__(256) void k_gemm(
    const unsigned int* __restrict__ Ag,    // [8][srows][64] bf16x2
    const unsigned int* __restrict__ xin,   // [N][64] bf16x2 (root chunk)
    unsigned int* __restrict__ xout,        // [N][64] bf16x2
    const unsigned short* __restrict__ WT,  // [9][128(n)][128(k)] bf16
    const float* __restrict__ bias,         // [128]
    int d0, int srows)
{
    __shared__ __align__(16) uint4 AslV[64 * 16];    // 16 KB swizzled
    __shared__ __align__(16) uint4 BslV[128 * 16];   // 32 KB swizzled
    const int t = threadIdx.x;
    const int wv = t >> 6, lane = t & 63;
    const int quad = lane >> 4, l15 = lane & 15;
    const int m0 = d0 + blockIdx.x * BM;

    const unsigned short* Abfs = (const unsigned short*)AslV;
    const unsigned short* Bbfs = (const unsigned short*)BslV;

    float4v acc[8];
#pragma unroll
    for (int nt = 0; nt < 8; ++nt) {
        float bc = bias[nt * 16 + l15];
        acc[nt] = (float4v){bc, bc, bc, bc};
    }

    for (int c = 0; c < 9; ++c) {
        __syncthreads();
        {
            const uint4* Wc = (const uint4*)(WT + c * 16384);
#pragma unroll
            for (int i = 0; i < 8; ++i) {
                int idx = t + 256 * i;
                BslV[gswz(idx >> 4, idx & 15)] = Wc[idx];
            }
        }
        {
            const uint4* Ac = (c < 8)
                ? (const uint4*)(Ag + ((size_t)c * srows + (m0 - d0)) * 64)
                : (const uint4*)(xin + (size_t)m0 * 64);   // root; tail over-read stays in ws
#pragma unroll
            for (int i = 0; i < 4; ++i) {
                int idx = t + 256 * i;
                AslV[gswz(idx >> 4, idx & 15)] = Ac[idx];
            }
        }
        __syncthreads();
#pragma unroll
        for (int kk = 0; kk < 4; ++kk) {
            int g = kk * 4 + quad;
            short8 a = *(const short8*)(Abfs + gswz(wv * 16 + l15, g) * 8);
#pragma unroll
            for (int nt = 0; nt < 8; ++nt) {
                short8 b = *(const short8*)(Bbfs + gswz(nt * 16 + l15, g) * 8);
                acc[nt] = __builtin_amdgcn_mfma_f32_16x16x32_bf16(a, b, acc[nt], 0, 0, 0);
            }
        }
    }
    // epilogue: relu, store bf16
    unsigned short* outs = (unsigned short*)xout;
#pragma unroll
    for (int nt = 0; nt < 8; ++nt) {
        int colg = nt * 16 + l15;
#pragma unroll
        for (int i = 0; i < 4; ++i) {
            int row = m0 + wv * 16 + quad * 4 + i;
            if (row < N_NODES) {
                float v = acc[nt][i];
                v = v > 0.f ? v : 0.f;
                outs[(size_t)row * 128 + colg] = f2bf(v);
            }
        }
    }
}

// ---------------- FALLBACK (round-1 fused layer; used only if ws too small) ----------------
__global__ __launch_bounds__(256) void k_layer_fb(
    const unsigned int* __restrict__ xin, unsigned int* __restrict__ xout,
    const int* __restrict__ rowptr, const int* __restrict__ srcs,
    const unsigned short* __restrict__ WT, const float* __restrict__ bias)
{
    __shared__ __align__(16) unsigned int Als[BM * 68];
    __shared__ __align__(16) unsigned int Bls[128 * 68];
    const int t = threadIdx.x;
    const int wv = t >> 6, lane = t & 63;
    const int quad = lane >> 4, l15 = lane & 15;
    const int m0 = blockIdx.x * BM;
    const int col2 = t & 63;
    const int rq = t >> 6;

    float4v acc[8];
#pragma unroll
    for (int nt = 0; nt < 8; ++nt) {
        float bc = bias[nt * 16 + l15];
        acc[nt] = (float4v){bc, bc, bc, bc};
    }
    for (int c = 0; c < 9; ++c) {
        if (c < 8) {
            for (int i = 0; i < 16; ++i) {
                int ml = rq + 4 * i;
                int m = m0 + ml;
                float a0 = 0.f, a1 = 0.f, inv = 0.f;
                if (m < N_NODES) {
                    int seg = m * N_REL + c;
                    int s = rowptr[seg], e = rowptr[seg + 1];
                    if (e > s) inv = 1.0f / (float)(e - s);
                    for (int j = s; j < e; ++j) {
                        unsigned int u = xin[(size_t)srcs[j] * 64 + col2];
                        a0 += bflo(u);
                        a1 += bfhi(u);
                    }
                }
                Als[ml * 68 + col2] = pack2(a0 * inv, a1 * inv);
            }
        } else {
            for (int i = 0; i < 16; ++i) {
                int ml = rq + 4 * i;
                int m = m0 + ml;
                Als[ml * 68 + col2] = (m < N_NODES) ? xin[(size_t)m * 64 + col2] : 0u;
            }
        }
        {
            const unsigned int* Wc = (const unsigned int*)(WT + c * 16384);
#pragma unroll
            for (int i = 0; i < 32; ++i) {
                int idx = t + 256 * i;
                Bls[(idx >> 6) * 68 + (idx & 63)] = Wc[idx];
            }
        }
        __syncthreads();
        const short* As = (const short*)Als;
        const short* Bs = (const short*)Bls;
#pragma unroll
        for (int kk = 0; kk < 4; ++kk) {
            short8 a = *(const short8*)(As + (wv * 16 + l15) * 136 + kk * 32 + quad * 8);
#pragma unroll
            for (int nt = 0; nt < 8; ++nt) {
                short8 b = *(const short8*)(Bs + (nt * 16 + l15) * 136 + kk * 32 + quad * 8);
                acc[nt] = __builtin_amdgcn_mfma_f32_16x16x32_bf16(a, b, acc[nt], 0, 0, 0);
            }
        }
        __syncthreads();
    }
    unsigned short* outs = (unsigned short*)xout;
#pragma unroll
    for (int nt = 0; nt < 8; ++nt) {
        int colg = nt * 16 + l15;
#pragma unroll
        for (int i = 0; i < 4; ++i) {
            int row = m0 + wv * 16 + quad * 4 + i;
            if (row < N_NODES) {
                float v = acc[nt][i];
                v = v > 0.f ? v : 0.f;
                outs[(size_t)row * 128 + colg] = f2bf(v);
            }
        }
    }
}

// ---------------- global mean pool (batch sorted): 64 nodes per wave ----------------
__global__ __launch_bounds__(256) void k_pool(const unsigned int* __restrict__ x2,
                                              const int* __restrict__ batch,
                                              float* __restrict__ gsum,
                                              int* __restrict__ gcnt) {
    const int wv = threadIdx.x >> 6, lane = threadIdx.x & 63;
    const int n0 = (blockIdx.x * 4 + wv) * 64;
    if (n0 >= N_NODES) return;
    int n1 = n0 + 64;
    if (n1 > N_NODES) n1 = N_NODES;
    const int nb = n1 - n0;
    // lane-indexed batch ids for this wave's 64 nodes
    int bb = batch[n0 + (lane < nb ? lane : nb - 1)];
    float a0 = 0.f, a1 = 0.f;
    int run = 0;
    int cur = __shfl(bb, 0);
    for (int base = 0; base < nb; base += 8) {
        unsigned int u[8];
        int m = nb - base;
#pragma unroll
        for (int q = 0; q < 8; ++q)
            if (q < m) u[q] = x2[(size_t)(n0 + base + q) * 64 + lane];
#pragma unroll
        for (int q = 0; q < 8; ++q) {
            if (q < m) {
                int b = __shfl(bb, base + q);
                if (b != cur) {
                    atomicAdd(&gsum[cur * 128 + lane * 2], a0);
                    atomicAdd(&gsum[cur * 128 + lane * 2 + 1], a1);
                    if (lane == 0) atomicAdd(&gcnt[cur], run);
                    a0 = a1 = 0.f;
                    run = 0;
                    cur = b;
                }
                a0 += bflo(u[q]);
                a1 += bfhi(u[q]);
                ++run;
            }
        }
    }
    atomicAdd(&gsum[cur * 128 + lane * 2], a0);
    atomicAdd(&gsum[cur * 128 + lane * 2 + 1], a1);
    if (lane == 0) atomicAdd(&gcnt[cur], run);
}

// ---------------- MLP heads (fp32) ----------------
__global__ __launch_bounds__(128) void k_heads(
    const float* __restrict__ gsum, const int* __restrict__ gcnt,
    const float* __restrict__ rw1, const float* __restrict__ rb1,
    const float* __restrict__ rw2, const float* __restrict__ rb2,
    const float* __restrict__ sw1, const float* __restrict__ sb1,
    const float* __restrict__ sw2, const float* __restrict__ sb2,
    float* __restrict__ out) {
    __shared__ float g[128];
    __shared__ float parts[2];
    int b = blockIdx.x, t = threadIdx.x;
    int c = gcnt[b];
    float invc = 1.0f / (float)(c > 0 ? c : 1);
    g[t] = gsum[b * 128 + t] * invc;
    __syncthreads();
    float acc = rb1[t];
    for (int d = 0; d < 128; ++d) acc += g[d] * rw1[d * 128 + t];
    float h = acc > 0.f ? acc : 0.f;
    float p = h * rw2[t];
    for (int o = 32; o > 0; o >>= 1) p += __shfl_down(p, o);
    if ((t & 63) == 0) parts[t >> 6] = p;
    __syncthreads();
    if (t == 0) out[b] = parts[0] + parts[1] + rb2[0];
    __syncthreads();
    acc = sb1[t];
    for (int d = 0; d < 128; ++d) acc += g[d] * sw1[d * 128 + t];
    h = acc > 0.f ? acc : 0.f;
    p = h * sw2[t];
    for (int o = 32; o > 0; o >>= 1) p += __shfl_down(p, o);
    if ((t & 63) == 0) parts[t >> 6] = p;
    __syncthreads();
    if (t == 0) out[64 + b] = parts[0] + parts[1] + sb2[0];
}

extern "C" void kernel_launch(void* const* d_in, const int* in_sizes, int n_in,
                              void* d_out, int out_size, void* d_ws, size_t ws_size,
                              hipStream_t stream) {
    const int*   node_type  = (const int*)d_in[0];
    const int*   edge_index = (const int*)d_in[1];
    const int*   edge_type  = (const int*)d_in[2];
    const int*   batch      = (const int*)d_in[3];
    const float* node_emb   = (const float*)d_in[4];
    const float* rel_w      = (const float*)d_in[5];
    const float* root_w     = (const float*)d_in[6];
    const float* bias       = (const float*)d_in[7];
    const float* rw1        = (const float*)d_in[8];
    const float* rb1        = (const float*)d_in[9];
    const float* rw2        = (const float*)d_in[10];
    const float* rb2        = (const float*)d_in[11];
    const float* sw1        = (const float*)d_in[12];
    const float* sb1        = (const float*)d_in[13];
    const float* sw2        = (const float*)d_in[14];
    const float* sb2        = (const float*)d_in[15];
    float* out = (float*)d_out;

    char* ws = (char*)d_ws;
    size_t off = 0;
    auto alloc = [&](size_t bytes) -> void* {
        void* p = ws + off;
        off += (bytes + 255) & ~(size_t)255;
        return p;
    };
    // ---- persistent region ----
    unsigned int*   xa     = (unsigned int*)alloc((size_t)N_NODES * 64 * 4);
    unsigned int*   xb     = (unsigned int*)alloc((size_t)N_NODES * 64 * 4);
    int*            rowptr = (int*)alloc((size_t)(NR + 1) * 4);
    int*            srcs   = (int*)alloc((size_t)N_EDGES * 4);
    int*            bsum   = (int*)alloc(1024 * 4);
    unsigned short* WT     = (unsigned short*)alloc((size_t)N_LAYER * 9 * 16384 * 2);
    float*          gsum   = (float*)alloc((64 * 128 + 64) * 4);
    int*            gcnt   = (int*)(gsum + 64 * 128);
    size_t off_common = off;
    // ---- scratch region: sort temps, later overlapped by Ag slices ----
    int*            cursor = (int*)alloc((size_t)NR * 4);
    int*            counts = (int*)alloc((size_t)NR * 4);
    size_t off_sort = off;
    if (off_sort > ws_size) return;                // cannot run at all
    unsigned int*   Ag     = (unsigned int*)(ws + off_common);  // overlaps cursor/counts
    size_t avail = ws_size - off_common;
    long max_rows = (long)(avail / 2048);          // bytes per node-row: 8 planes * 256 B
    int srows = (int)((max_rows / 64) * 64);
    if (srows > N_NODES + 63) srows = ((N_NODES + 63) / 64) * 64;
    const bool split_ok = (srows >= 64);

    // edge sort (counting sort by dst*8 + rel)
    k_zero<<<(NR + 255) / 256, 256, 0, stream>>>(counts, NR);
    k_zero<<<(64 * 128 + 64 + 255) / 256, 256, 0, stream>>>((int*)gsum, 64 * 128 + 64);
    k_hist<<<(N_EDGES + 255) / 256, 256, 0, stream>>>(edge_index, edge_type, counts);
    k_scan1<<<NB1, 256, 0, stream>>>(counts, cursor, bsum);
    k_scan2<<<1, 1024, 0, stream>>>(bsum, NB1);
    k_scan3<<<(NR + 255) / 256, 256, 0, stream>>>(cursor, bsum, rowptr, cursor);
    k_scatter<<<(N_EDGES + 255) / 256, 256, 0, stream>>>(edge_index, edge_type, cursor, srcs);

    // x0 gather + weight prep
    k_gather<<<(N_NODES * 64 + 255) / 256, 256, 0, stream>>>(node_type, node_emb, xa);
    k_wprep<<<(N_LAYER * 9 * 16384 + 255) / 256, 256, 0, stream>>>(rel_w, root_w, WT);

    const int mblocks = (N_NODES + BM - 1) / BM;   // 1563
    unsigned int* xcur = xa;
    unsigned int* xnext = xb;
    for (int l = 0; l < N_LAYER; ++l) {
        const unsigned short* Wl = WT + (size_t)l * 9 * 16384;
        const float* bl = bias + (size_t)l * 128;
        if (split_ok) {
            for (int d0 = 0; d0 < N_NODES; d0 += srows) {
                int rows = N_NODES - d0;
                if (rows > srows) rows = srows;
                int ab = (rows + 3) / 4;
                int gb = (rows + BM - 1) / BM;
                k_agg<<<ab, 256, 0, stream>>>(xcur, rowptr, srcs, Ag, d0, rows, srows);
                k_gemm<<<gb, 256, 0, stream>>>(Ag, xcur, xnext, Wl, bl, d0, srows);
            }
        } else {
            k_layer_fb<<<mblocks, 256, 0, stream>>>(xcur, xnext, rowptr, srcs, Wl, bl);
        }
        unsigned int* tmp = xcur; xcur = xnext; xnext = tmp;
    }

    // pool + heads (final activations are in xcur after swap)
    k_pool<<<(N_NODES + 255) / 256, 256, 0, stream>>>(xcur, batch, gsum, gcnt);
    k_heads<<<64, 128, 0, stream>>>(gsum, gcnt, rw1, rb1, rw2, rb2,
                                    sw1, sb1, sw2, sb2, out);
}

// Round 7
// 596.067 us; speedup vs baseline: 3.5851x; 1.0549x over previous
//
#include <hip/hip_runtime.h>
#include <hip/hip_bf16.h>

#define N_NODES 100000
#define N_EDGES 600000
#define DIM     128
#define N_REL   8
#define N_GRAPH 64
#define N_LAYER 3
#define NR      (N_NODES * N_REL)   // 800000
#define NB1     782                 // ceil(NR / 1024)

typedef __attribute__((ext_vector_type(8))) short short8;
typedef __attribute__((ext_vector_type(4))) float float4v;

__device__ __forceinline__ float bflo(unsigned int u) {
    return __builtin_bit_cast(float, u << 16);
}
__device__ __forceinline__ float bfhi(unsigned int u) {
    return __builtin_bit_cast(float, u & 0xffff0000u);
}
__device__ __forceinline__ unsigned short f2bf(float f) {
    unsigned int u = __builtin_bit_cast(unsigned int, f);
    u += 0x7fffu + ((u >> 16) & 1u);          // RNE
    return (unsigned short)(u >> 16);
}
__device__ __forceinline__ unsigned int pack2(float a, float b) {
    return (unsigned int)f2bf(a) | ((unsigned int)f2bf(b) << 16);
}
// XOR-swizzled granule index (16-B granules, 256-B rows — bf16 tiles)
__device__ __forceinline__ int gswz(int row, int g) {
    return row * 16 + (g ^ (row & 15));
}
// XOR-swizzled granule index (8-B granules, 128-B rows — fp8 tiles)
__device__ __forceinline__ int gswz8(int row, int g) {
    return row * 16 + (g ^ (row & 15));
}

// ---------------- utility: zero int buffer ----------------
__global__ void k_zero(int* __restrict__ p, int n) {
    int i = blockIdx.x * 256 + threadIdx.x;
    if (i < n) p[i] = 0;
}

// ---------------- counting sort of edges by seg = dst*8 + rel (dst-major) ----------------
__global__ void k_hist(const int* __restrict__ ei, const int* __restrict__ et,
                       int* __restrict__ counts) {
    int e = blockIdx.x * 256 + threadIdx.x;
    if (e < N_EDGES) {
        int seg = ei[N_EDGES + e] * N_REL + et[e];
        atomicAdd(&counts[seg], 1);
    }
}

__global__ __launch_bounds__(256) void k_scan1(const int* __restrict__ cnts,
                                               int* __restrict__ part,
                                               int* __restrict__ bsum) {
    __shared__ int sh[256];
    int t = threadIdx.x;
    int base = blockIdx.x * 1024 + t * 4;
    int v0 = (base + 0 < NR) ? cnts[base + 0] : 0;
    int v1 = (base + 1 < NR) ? cnts[base + 1] : 0;
    int v2 = (base + 2 < NR) ? cnts[base + 2] : 0;
    int v3 = (base + 3 < NR) ? cnts[base + 3] : 0;
    int tot = v0 + v1 + v2 + v3;
    sh[t] = tot;
    __syncthreads();
    for (int off = 1; off < 256; off <<= 1) {
        int x = (t >= off) ? sh[t - off] : 0;
        __syncthreads();
        sh[t] += x;
        __syncthreads();
    }
    int exc = sh[t] - tot;
    if (base + 0 < NR) part[base + 0] = exc;
    if (base + 1 < NR) part[base + 1] = exc + v0;
    if (base + 2 < NR) part[base + 2] = exc + v0 + v1;
    if (base + 3 < NR) part[base + 3] = exc + v0 + v1 + v2;
    if (t == 255) bsum[blockIdx.x] = sh[t];
}

__global__ __launch_bounds__(1024) void k_scan2(int* __restrict__ bsum, int nb) {
    __shared__ int sh[1024];
    int t = threadIdx.x;
    int v = (t < nb) ? bsum[t] : 0;
    sh[t] = v;
    __syncthreads();
    for (int off = 1; off < 1024; off <<= 1) {
        int x = (t >= off) ? sh[t - off] : 0;
        __syncthreads();
        sh[t] += x;
        __syncthreads();
    }
    if (t < nb) bsum[t] = sh[t] - v;   // exclusive block offsets
}

__global__ void k_scan3(const int* __restrict__ part, const int* __restrict__ bsum,
                        int* __restrict__ rowptr, int* __restrict__ cursor) {
    int i = blockIdx.x * 256 + threadIdx.x;
    if (i < NR) {
        int v = part[i] + bsum[i >> 10];
        rowptr[i] = v;
        cursor[i] = v;
    }
    if (i == 0) rowptr[NR] = N_EDGES;
}

__global__ void k_scatter(const int* __restrict__ ei, const int* __restrict__ et,
                          int* __restrict__ cursor, int* __restrict__ srcs) {
    int e = blockIdx.x * 256 + threadIdx.x;
    if (e < N_EDGES) {
        int seg = ei[N_EDGES + e] * N_REL + et[e];
        int p = atomicAdd(&cursor[seg], 1);
        srcs[p] = ei[e];
    }
}

// ---------------- x0 = node_emb[node_type], stored bf16x2 ----------------
__global__ void k_gather(const int* __restrict__ nt, const float* __restrict__ emb,
                         unsigned int* __restrict__ x2) {
    int gid = blockIdx.x * 256 + threadIdx.x;
    if (gid < N_NODES * 64) {
        int n = gid >> 6, c2 = gid & 63;
        const float* row = emb + (size_t)nt[n] * DIM + c2 * 2;
        x2[gid] = pack2(row[0], row[1]);
    }
}

// ---------------- weight prep: bf16 WT (root uses chunk 8) ----------------
__global__ void k_wprep(const float* __restrict__ relw, const float* __restrict__ rootw,
                        unsigned short* __restrict__ WT) {
    int gid = blockIdx.x * 256 + threadIdx.x;
    if (gid < N_LAYER * 9 * 16384) {
        int l = gid / (9 * 16384);
        int rem = gid - l * 9 * 16384;
        int c = rem >> 14;
        int idx = rem & 16383;
        int n = idx >> 7, k = idx & 127;
        float w = (c < 8) ? relw[(((size_t)l * 8 + c) * 128 + k) * 128 + n]
                          : rootw[((size_t)l * 128 + k) * 128 + n];
        WT[gid] = f2bf(w);
    }
}

// ---------------- weight prep: fp8 e4m3 rel planes, [l][r][n][k] ----------------
__global__ void k_wprep8(const float* __restrict__ relw, unsigned short* __restrict__ W8) {
    int gid = blockIdx.x * 256 + threadIdx.x;      // over L*8*128n*64kpair
    if (gid < N_LAYER * 8 * 8192) {
        int l = gid / (8 * 8192);
        int rem = gid - l * 8 * 8192;
        int r = rem >> 13;
        int idx = rem & 8191;
        int n = idx >> 6, kp = idx & 63;
        const float* base = relw + (((size_t)(l * 8 + r) * 128) * 128) + n;
        float w0 = base[(size_t)(2 * kp) * 128];
        float w1 = base[(size_t)(2 * kp + 1) * 128];
        int pk = __builtin_amdgcn_cvt_pk_fp8_f32(w0, w1, 0, false);
        W8[gid] = (unsigned short)(pk & 0xffff);
    }
}

// ---------------- per-dst aggregation, one wave per node (sliced), fp8 out ----------------
#define PF 16
__global__ __launch_bounds__(256) void k_agg(
    const unsigned int* __restrict__ xin,   // [N][64] bf16x2
    const int* __restrict__ rowptr,         // [NR+1], seg = dst*8 + rel
    const int* __restrict__ srcs,           // [E] sorted by seg
    unsigned int* __restrict__ Ag8,         // [8][srows][32] fp8x4
    int d0, int rows, int srows)
{
    __shared__ unsigned int eshm[4 * PF * 64];   // 16 KB: per-wave prefetch buffer
    const int t = threadIdx.x;
    const int wv = t >> 6, lane = t & 63;
    const int dl = blockIdx.x * 4 + wv;
    if (dl >= rows) return;
    const int d = d0 + dl;
    const int wvoff = wv * PF * 64;

    int pr = 0;
    if (lane < 9) pr = rowptr[d * 8 + lane];
    const int p0 = __shfl(pr, 0);
    const int deg = __shfl(pr, 8) - p0;

    int my_src = 0;
    if (lane < deg) my_src = srcs[p0 + lane];

#pragma unroll
    for (int q = 0; q < PF; ++q) {
        if (q < deg) {
            int s = __shfl(my_src, q);
            eshm[wvoff + q * 64 + lane] = xin[(size_t)s * 64 + lane];
        }
    }

#pragma unroll
    for (int r = 0; r < 8; ++r) {
        int e0 = __shfl(pr, r) - p0;
        int e1 = __shfl(pr, r + 1) - p0;
        int cnt = e1 - e0;
        float a0 = 0.f, a1 = 0.f;
        for (int k = e0; k < e1; ++k) {          // wave-uniform loop
            unsigned int v;
            if (k < PF) {
                v = eshm[wvoff + k * 64 + lane];
            } else {
                int s = (k < 64) ? __shfl(my_src, k) : srcs[p0 + k];
                v = xin[(size_t)s * 64 + lane];
            }
            a0 += bflo(v);
            a1 += bfhi(v);
        }
        float inv = (cnt > 0) ? 1.0f / (float)cnt : 0.f;
        // fp8 pack: lane l holds cols 2l,2l+1 -> ushort; pair lanes -> uint (cols 4j..4j+3)
        unsigned int us = (unsigned int)__builtin_amdgcn_cvt_pk_fp8_f32(a0 * inv, a1 * inv, 0, false) & 0xffffu;
        unsigned int other = (unsigned int)__shfl_xor((int)us, 1);
        if (!(lane & 1))
            Ag8[((size_t)r * srows + dl) * 32 + (lane >> 1)] = us | (other << 16);
    }
}

// ---------------- dense MFMA GEMM: 8 fp8 chunks + 1 bf16 root chunk ----------------
#define BM 64
__global__ __launch_bounds__(256) void k_gemm(
    const unsigned int* __restrict__ Ag8,   // [8][srows][32] fp8x4
    const unsigned int* __restrict__ xin,   // [N][64] bf16x2 (root chunk)
    unsigned int* __restrict__ xout,        // [N][64] bf16x2
    const unsigned short* __restrict__ W8,  // [8][128n][64kp] fp8 pairs (this layer)
    const unsigned short* __restrict__ WT,  // [9][128n][128k] bf16 (this layer; root = chunk 8)
    const float* __restrict__ bias,         // [128]
    int d0, int srows)
{
    __shared__ __align__(16) uint4 AslV[64 * 16];    // 16 KB (fp8 A uses first 8 KB)
    __shared__ __align__(16) uint4 BslV[128 * 16];   // 32 KB (fp8 B uses first 16 KB)
    const int t = threadIdx.x;
    const int wv = t >> 6, lane = t & 63;
    const int quad = lane >> 4, l15 = lane & 15;
    const int m0 = d0 + blockIdx.x * BM;

    const unsigned short* Abfs = (const unsigned short*)AslV;
    const unsigned short* Bbfs = (const unsigned short*)BslV;
    unsigned long long* A8l = (unsigned long long*)AslV;
    unsigned long long* B8l = (unsigned long long*)BslV;

    float4v acc[8];
#pragma unroll
    for (int nt = 0; nt < 8; ++nt) {
        float bc = bias[nt * 16 + l15];
        acc[nt] = (float4v){bc, bc, bc, bc};
    }

    // ---- 8 fp8 chunks ----
    for (int c = 0; c < 8; ++c) {
        __syncthreads();
        {   // stage B fp8: 16 KB = 2048 x 8 B
            const unsigned long long* Wc = (const unsigned long long*)(W8 + (size_t)c * 8192);
#pragma unroll
            for (int i = 0; i < 8; ++i) {
                int idx = t + 256 * i;            // granule id, row=idx>>4, g=idx&15
                B8l[gswz8(idx >> 4, idx & 15)] = Wc[idx];
            }
        }
        {   // stage A fp8: 8 KB = 1024 x 8 B
            const unsigned long long* Ac = (const unsigned long long*)(Ag8 + ((size_t)c * srows + (m0 - d0)) * 32);
#pragma unroll
            for (int i = 0; i < 4; ++i) {
                int idx = t + 256 * i;
                A8l[gswz8(idx >> 4, idx & 15)] = Ac[idx];
            }
        }
        __syncthreads();
#pragma unroll
        for (int kk = 0; kk < 4; ++kk) {
            int g = kk * 4 + quad;
            long long a8 = (long long)A8l[(wv * 16 + l15) * 16 + (g ^ l15)];
#pragma unroll
            for (int nt = 0; nt < 8; ++nt) {
                long long b8 = (long long)B8l[(nt * 16 + l15) * 16 + (g ^ l15)];
                acc[nt] = __builtin_amdgcn_mfma_f32_16x16x32_fp8_fp8(a8, b8, acc[nt], 0, 0, 0);
            }
        }
    }
    // ---- root chunk (bf16): A = xin rows, B = WT chunk 8 ----
    __syncthreads();
    {
        const uint4* Wc = (const uint4*)(WT + 8 * 16384);
#pragma unroll
        for (int i = 0; i < 8; ++i) {
            int idx = t + 256 * i;
            BslV[gswz(idx >> 4, idx & 15)] = Wc[idx];
        }
        const uint4* Ac = (const uint4*)(xin + (size_t)m0 * 64);
#pragma unroll
        for (int i = 0; i < 4; ++i) {
            int idx = t + 256 * i;
            AslV[gswz(idx >> 4, idx & 15)] = Ac[idx];
        }
    }
    __syncthreads();
#pragma unroll
    for (int kk = 0; kk < 4; ++kk) {
        int g = kk * 4 + quad;
        short8 a = *(const short8*)(Abfs + gswz(wv * 16 + l15, g) * 8);
#pragma unroll
        for (int nt = 0; nt < 8; ++nt) {
            short8 b = *(const short8*)(Bbfs + gswz(nt * 16 + l15, g) * 8);
            acc[nt] = __builtin_amdgcn_mfma_f32_16x16x32_bf16(a, b, acc[nt], 0, 0, 0);
        }
    }
    // ---- epilogue: relu, store bf16 ----
    unsigned short* outs = (unsigned short*)xout;
#pragma unroll
    for (int nt = 0; nt < 8; ++nt) {
        int colg = nt * 16 + l15;
#pragma unroll
        for (int i = 0; i < 4; ++i) {
            int row = m0 + wv * 16 + quad * 4 + i;
            if (row < N_NODES) {
                float v = acc[nt][i];
                v = v > 0.f ? v : 0.f;
                outs[(size_t)row * 128 + colg] = f2bf(v);
            }
        }
    }
}

// ---------------- FALLBACK (fused layer; used only if ws too small) ----------------
__global__ __launch_bounds__(256) void k_layer_fb(
    const unsigned int* __restrict__ xin, unsigned int* __restrict__ xout,
    const int* __restrict__ rowptr, const int* __restrict__ srcs,
    const unsigned short* __restrict__ WT, const float* __restrict__ bias)
{
    __shared__ __align__(16) unsigned int Als[BM * 68];
    __shared__ __align__(16) unsigned int Bls[128 * 68];
    const int t = threadIdx.x;
    const int wv = t >> 6, lane = t & 63;
    const int quad = lane >> 4, l15 = lane & 15;
    const int m0 = blockIdx.x * BM;
    const int col2 = t & 63;
    const int rq = t >> 6;

    float4v acc[8];
#pragma unroll
    for (int nt = 0; nt < 8; ++nt) {
        float bc = bias[nt * 16 + l15];
        acc[nt] = (float4v){bc, bc, bc, bc};
    }
    for (int c = 0; c < 9; ++c) {
        if (c < 8) {
            for (int i = 0; i < 16; ++i) {
                int ml = rq + 4 * i;
                int m = m0 + ml;
                float a0 = 0.f, a1 = 0.f, inv = 0.f;
                if (m < N_NODES) {
                    int seg = m * N_REL + c;
                    int s = rowptr[seg], e = rowptr[seg + 1];
                    if (e > s) inv = 1.0f / (float)(e - s);
                    for (int j = s; j < e; ++j) {
                        unsigned int u = xin[(size_t)srcs[j] * 64 + col2];
                        a0 += bflo(u);
                        a1 += bfhi(u);
                    }
                }
                Als[ml * 68 + col2] = pack2(a0 * inv, a1 * inv);
            }
        } else {
            for (int i = 0; i < 16; ++i) {
                int ml = rq + 4 * i;
                int m = m0 + ml;
                Als[ml * 68 + col2] = (m < N_NODES) ? xin[(size_t)m * 64 + col2] : 0u;
            }
        }
        {
            const unsigned int* Wc = (const unsigned int*)(WT + c * 16384);
#pragma unroll
            for (int i = 0; i < 32; ++i) {
                int idx = t + 256 * i;
                Bls[(idx >> 6) * 68 + (idx & 63)] = Wc[idx];
            }
        }
        __syncthreads();
        const short* As = (const short*)Als;
        const short* Bs = (const short*)Bls;
#pragma unroll
        for (int kk = 0; kk < 4; ++kk) {
            short8 a = *(const short8*)(As + (wv * 16 + l15) * 136 + kk * 32 + quad * 8);
#pragma unroll
            for (int nt = 0; nt < 8; ++nt) {
                short8 b = *(const short8*)(Bs + (nt * 16 + l15) * 136 + kk * 32 + quad * 8);
                acc[nt] = __builtin_amdgcn_mfma_f32_16x16x32_bf16(a, b, acc[nt], 0, 0, 0);
            }
        }
        __syncthreads();
    }
    unsigned short* outs = (unsigned short*)xout;
#pragma unroll
    for (int nt = 0; nt < 8; ++nt) {
        int colg = nt * 16 + l15;
#pragma unroll
        for (int i = 0; i < 4; ++i) {
            int row = m0 + wv * 16 + quad * 4 + i;
            if (row < N_NODES) {
                float v = acc[nt][i];
                v = v > 0.f ? v : 0.f;
                outs[(size_t)row * 128 + colg] = f2bf(v);
            }
        }
    }
}

// ---------------- global mean pool (batch sorted): 64 nodes per wave ----------------
__global__ __launch_bounds__(256) void k_pool(const unsigned int* __restrict__ x2,
                                              const int* __restrict__ batch,
                                              float* __restrict__ gsum,
                                              int* __restrict__ gcnt) {
    const int wv = threadIdx.x >> 6, lane = threadIdx.x & 63;
    const int n0 = (blockIdx.x * 4 + wv) * 64;
    if (n0 >= N_NODES) return;
    int n1 = n0 + 64;
    if (n1 > N_NODES) n1 = N_NODES;
    const int nb = n1 - n0;
    int bb = batch[n0 + (lane < nb ? lane : nb - 1)];
    float a0 = 0.f, a1 = 0.f;
    int run = 0;
    int cur = __shfl(bb, 0);
    for (int base = 0; base < nb; base += 8) {
        unsigned int u[8];
        int m = nb - base;
#pragma unroll
        for (int q = 0; q < 8; ++q)
            if (q < m) u[q] = x2[(size_t)(n0 + base + q) * 64 + lane];
#pragma unroll
        for (int q = 0; q < 8; ++q) {
            if (q < m) {
                int b = __shfl(bb, base + q);
                if (b != cur) {
                    atomicAdd(&gsum[cur * 128 + lane * 2], a0);
                    atomicAdd(&gsum[cur * 128 + lane * 2 + 1], a1);
                    if (lane == 0) atomicAdd(&gcnt[cur], run);
                    a0 = a1 = 0.f;
                    run = 0;
                    cur = b;
                }
                a0 += bflo(u[q]);
                a1 += bfhi(u[q]);
                ++run;
            }
        }
    }
    atomicAdd(&gsum[cur * 128 + lane * 2], a0);
    atomicAdd(&gsum[cur * 128 + lane * 2 + 1], a1);
    if (lane == 0) atomicAdd(&gcnt[cur], run);
}

// ---------------- MLP heads (fp32) ----------------
__global__ __launch_bounds__(128) void k_heads(
    const float* __restrict__ gsum, const int* __restrict__ gcnt,
    const float* __restrict__ rw1, const float* __restrict__ rb1,
    const float* __restrict__ rw2, const float* __restrict__ rb2,
    const float* __restrict__ sw1, const float* __restrict__ sb1,
    const float* __restrict__ sw2, const float* __restrict__ sb2,
    float* __restrict__ out) {
    __shared__ float g[128];
    __shared__ float parts[2];
    int b = blockIdx.x, t = threadIdx.x;
    int c = gcnt[b];
    float invc = 1.0f / (float)(c > 0 ? c : 1);
    g[t] = gsum[b * 128 + t] * invc;
    __syncthreads();
    float acc = rb1[t];
    for (int d = 0; d < 128; ++d) acc += g[d] * rw1[d * 128 + t];
    float h = acc > 0.f ? acc : 0.f;
    float p = h * rw2[t];
    for (int o = 32; o > 0; o >>= 1) p += __shfl_down(p, o);
    if ((t & 63) == 0) parts[t >> 6] = p;
    __syncthreads();
    if (t == 0) out[b] = parts[0] + parts[1] + rb2[0];
    __syncthreads();
    acc = sb1[t];
    for (int d = 0; d < 128; ++d) acc += g[d] * sw1[d * 128 + t];
    h = acc > 0.f ? acc : 0.f;
    p = h * sw2[t];
    for (int o = 32; o > 0; o >>= 1) p += __shfl_down(p, o);
    if ((t & 63) == 0) parts[t >> 6] = p;
    __syncthreads();
    if (t == 0) out[64 + b] = parts[0] + parts[1] + sb2[0];
}

extern "C" void kernel_launch(void* const* d_in, const int* in_sizes, int n_in,
                              void* d_out, int out_size, void* d_ws, size_t ws_size,
                              hipStream_t stream) {
    const int*   node_type  = (const int*)d_in[0];
    const int*   edge_index = (const int*)d_in[1];
    const int*   edge_type  = (const int*)d_in[2];
    const int*   batch      = (const int*)d_in[3];
    const float* node_emb   = (const float*)d_in[4];
    const float* rel_w      = (const float*)d_in[5];
    const float* root_w     = (const float*)d_in[6];
    const float* bias       = (const float*)d_in[7];
    const float* rw1        = (const float*)d_in[8];
    const float* rb1        = (const float*)d_in[9];
    const float* rw2        = (const float*)d_in[10];
    const float* rb2        = (const float*)d_in[11];
    const float* sw1        = (const float*)d_in[12];
    const float* sb1        = (const float*)d_in[13];
    const float* sw2        = (const float*)d_in[14];
    const float* sb2        = (const float*)d_in[15];
    float* out = (float*)d_out;

    char* ws = (char*)d_ws;
    size_t off = 0;
    auto alloc = [&](size_t bytes) -> void* {
        void* p = ws + off;
        off += (bytes + 255) & ~(size_t)255;
        return p;
    };
    // ---- persistent region ----
    unsigned int*   xa     = (unsigned int*)alloc((size_t)N_NODES * 64 * 4);
    unsigned int*   xb     = (unsigned int*)alloc((size_t)N_NODES * 64 * 4);
    int*            rowptr = (int*)alloc((size_t)(NR + 1) * 4);
    int*            srcs   = (int*)alloc((size_t)N_EDGES * 4);
    int*            bsum   = (int*)alloc(1024 * 4);
    unsigned short* WT     = (unsigned short*)alloc((size_t)N_LAYER * 9 * 16384 * 2);
    unsigned short* W8     = (unsigned short*)alloc((size_t)N_LAYER * 8 * 8192 * 2);
    float*          gsum   = (float*)alloc((64 * 128 + 64) * 4);
    int*            gcnt   = (int*)(gsum + 64 * 128);
    size_t off_common = off;
    // ---- scratch region: sort temps, later overlapped by Ag8 slices ----
    int*            cursor = (int*)alloc((size_t)NR * 4);
    int*            counts = (int*)alloc((size_t)NR * 4);
    size_t off_sort = off;
    if (off_sort > ws_size) return;                // cannot run at all
    unsigned int*   Ag8    = (unsigned int*)(ws + off_common);  // overlaps cursor/counts
    size_t avail = ws_size - off_common;
    long max_rows = (long)(avail / 1024);          // bytes per node-row: 8 planes * 128 B
    int srows = (int)((max_rows / 64) * 64);
    if (srows > N_NODES + 63) srows = ((N_NODES + 63) / 64) * 64;
    const bool split_ok = (srows >= 64);

    // edge sort (counting sort by dst*8 + rel)
    k_zero<<<(NR + 255) / 256, 256, 0, stream>>>(counts, NR);
    k_zero<<<(64 * 128 + 64 + 255) / 256, 256, 0, stream>>>((int*)gsum, 64 * 128 + 64);
    k_hist<<<(N_EDGES + 255) / 256, 256, 0, stream>>>(edge_index, edge_type, counts);
    k_scan1<<<NB1, 256, 0, stream>>>(counts, cursor, bsum);
    k_scan2<<<1, 1024, 0, stream>>>(bsum, NB1);
    k_scan3<<<(NR + 255) / 256, 256, 0, stream>>>(cursor, bsum, rowptr, cursor);
    k_scatter<<<(N_EDGES + 255) / 256, 256, 0, stream>>>(edge_index, edge_type, cursor, srcs);

    // x0 gather + weight prep (bf16 + fp8)
    k_gather<<<(N_NODES * 64 + 255) / 256, 256, 0, stream>>>(node_type, node_emb, xa);
    k_wprep<<<(N_LAYER * 9 * 16384 + 255) / 256, 256, 0, stream>>>(rel_w, root_w, WT);
    k_wprep8<<<(N_LAYER * 8 * 8192 + 255) / 256, 256, 0, stream>>>(rel_w, W8);

    const int mblocks = (N_NODES + BM - 1) / BM;   // 1563
    unsigned int* xcur = xa;
    unsigned int* xnext = xb;
    for (int l = 0; l < N_LAYER; ++l) {
        const unsigned short* Wl  = WT + (size_t)l * 9 * 16384;
        const unsigned short* W8l = W8 + (size_t)l * 8 * 8192;
        const float* bl = bias + (size_t)l * 128;
        if (split_ok) {
            for (int d0 = 0; d0 < N_NODES; d0 += srows) {
                int rows = N_NODES - d0;
                if (rows > srows) rows = srows;
                int ab = (rows + 3) / 4;
                int gb = (rows + BM - 1) / BM;
                k_agg<<<ab, 256, 0, stream>>>(xcur, rowptr, srcs, Ag8, d0, rows, srows);
                k_gemm<<<gb, 256, 0, stream>>>(Ag8, xcur, xnext, W8l, Wl, bl, d0, srows);
            }
        } else {
            k_layer_fb<<<mblocks, 256, 0, stream>>>(xcur, xnext, rowptr, srcs, Wl, bl);
        }
        unsigned int* tmp = xcur; xcur = xnext; xnext = tmp;
    }

    // pool + heads (final activations are in xcur after swap)
    k_pool<<<(N_NODES + 255) / 256, 256, 0, stream>>>(xcur, batch, gsum, gcnt);
    k_heads<<<64, 128, 0, stream>>>(gsum, gcnt, rw1, rb1, rw2, rb2,
                                    sw1, sb1, sw2, sb2, out);
}

// Round 8
// 474.297 us; speedup vs baseline: 4.5056x; 1.2567x over previous
//
#include <hip/hip_runtime.h>
#include <hip/hip_bf16.h>

#define N_NODES 100000
#define N_EDGES 600000
#define DIM     128
#define N_REL   8
#define N_GRAPH 64
#define N_LAYER 3
#define NR      (N_NODES * N_REL)   // 800000
#define NB1     782                 // ceil(NR / 1024)

typedef __attribute__((ext_vector_type(8))) short short8;
typedef __attribute__((ext_vector_type(4))) float float4v;

__device__ __forceinline__ float bflo(unsigned int u) {
    return __builtin_bit_cast(float, u << 16);
}
__device__ __forceinline__ float bfhi(unsigned int u) {
    return __builtin_bit_cast(float, u & 0xffff0000u);
}
__device__ __forceinline__ unsigned short f2bf(float f) {
    unsigned int u = __builtin_bit_cast(unsigned int, f);
    u += 0x7fffu + ((u >> 16) & 1u);          // RNE
    return (unsigned short)(u >> 16);
}
__device__ __forceinline__ unsigned int pack2(float a, float b) {
    return (unsigned int)f2bf(a) | ((unsigned int)f2bf(b) << 16);
}
// XOR-swizzled granule index (16-B granules, 256-B rows — bf16 tiles)
__device__ __forceinline__ int gswz(int row, int g) {
    return row * 16 + (g ^ (row & 15));
}
// XOR-swizzled granule index (8-B granules, 128-B rows — fp8 tiles)
__device__ __forceinline__ int gswz8(int row, int g) {
    return row * 16 + (g ^ (row & 15));
}

// ---------------- utility: zero int buffer ----------------
__global__ void k_zero(int* __restrict__ p, int n) {
    int i = blockIdx.x * 256 + threadIdx.x;
    if (i < n) p[i] = 0;
}

// ---------------- counting sort of edges by seg = dst*8 + rel (dst-major) ----------------
__global__ void k_hist(const int* __restrict__ ei, const int* __restrict__ et,
                       int* __restrict__ counts) {
    int e = blockIdx.x * 256 + threadIdx.x;
    if (e < N_EDGES) {
        int seg = ei[N_EDGES + e] * N_REL + et[e];
        atomicAdd(&counts[seg], 1);
    }
}

__global__ __launch_bounds__(256) void k_scan1(const int* __restrict__ cnts,
                                               int* __restrict__ part,
                                               int* __restrict__ bsum) {
    __shared__ int sh[256];
    int t = threadIdx.x;
    int base = blockIdx.x * 1024 + t * 4;
    int v0 = (base + 0 < NR) ? cnts[base + 0] : 0;
    int v1 = (base + 1 < NR) ? cnts[base + 1] : 0;
    int v2 = (base + 2 < NR) ? cnts[base + 2] : 0;
    int v3 = (base + 3 < NR) ? cnts[base + 3] : 0;
    int tot = v0 + v1 + v2 + v3;
    sh[t] = tot;
    __syncthreads();
    for (int off = 1; off < 256; off <<= 1) {
        int x = (t >= off) ? sh[t - off] : 0;
        __syncthreads();
        sh[t] += x;
        __syncthreads();
    }
    int exc = sh[t] - tot;
    if (base + 0 < NR) part[base + 0] = exc;
    if (base + 1 < NR) part[base + 1] = exc + v0;
    if (base + 2 < NR) part[base + 2] = exc + v0 + v1;
    if (base + 3 < NR) part[base + 3] = exc + v0 + v1 + v2;
    if (t == 255) bsum[blockIdx.x] = sh[t];
}

__global__ __launch_bounds__(1024) void k_scan2(int* __restrict__ bsum, int nb) {
    __shared__ int sh[1024];
    int t = threadIdx.x;
    int v = (t < nb) ? bsum[t] : 0;
    sh[t] = v;
    __syncthreads();
    for (int off = 1; off < 1024; off <<= 1) {
        int x = (t >= off) ? sh[t - off] : 0;
        __syncthreads();
        sh[t] += x;
        __syncthreads();
    }
    if (t < nb) bsum[t] = sh[t] - v;   // exclusive block offsets
}

__global__ void k_scan3(const int* __restrict__ part, const int* __restrict__ bsum,
                        int* __restrict__ rowptr, int* __restrict__ cursor) {
    int i = blockIdx.x * 256 + threadIdx.x;
    if (i < NR) {
        int v = part[i] + bsum[i >> 10];
        rowptr[i] = v;
        cursor[i] = v;
    }
    if (i == 0) rowptr[NR] = N_EDGES;
}

__global__ void k_scatter(const int* __restrict__ ei, const int* __restrict__ et,
                          int* __restrict__ cursor, int* __restrict__ srcs) {
    int e = blockIdx.x * 256 + threadIdx.x;
    if (e < N_EDGES) {
        int seg = ei[N_EDGES + e] * N_REL + et[e];
        int p = atomicAdd(&cursor[seg], 1);
        srcs[p] = ei[e];
    }
}

// ---------------- x0 = node_emb[node_type], stored bf16x2 ----------------
__global__ void k_gather(const int* __restrict__ nt, const float* __restrict__ emb,
                         unsigned int* __restrict__ x2) {
    int gid = blockIdx.x * 256 + threadIdx.x;
    if (gid < N_NODES * 64) {
        int n = gid >> 6, c2 = gid & 63;
        const float* row = emb + (size_t)nt[n] * DIM + c2 * 2;
        x2[gid] = pack2(row[0], row[1]);
    }
}

// ---------------- weight prep: bf16 WT (root uses chunk 8) ----------------
__global__ void k_wprep(const float* __restrict__ relw, const float* __restrict__ rootw,
                        unsigned short* __restrict__ WT) {
    int gid = blockIdx.x * 256 + threadIdx.x;
    if (gid < N_LAYER * 9 * 16384) {
        int l = gid / (9 * 16384);
        int rem = gid - l * 9 * 16384;
        int c = rem >> 14;
        int idx = rem & 16383;
        int n = idx >> 7, k = idx & 127;
        float w = (c < 8) ? relw[(((size_t)l * 8 + c) * 128 + k) * 128 + n]
                          : rootw[((size_t)l * 128 + k) * 128 + n];
        WT[gid] = f2bf(w);
    }
}

// ---------------- weight prep: fp8 e4m3 rel planes, [l][r][n][k] ----------------
__global__ void k_wprep8(const float* __restrict__ relw, unsigned short* __restrict__ W8) {
    int gid = blockIdx.x * 256 + threadIdx.x;      // over L*8*128n*64kpair
    if (gid < N_LAYER * 8 * 8192) {
        int l = gid / (8 * 8192);
        int rem = gid - l * 8 * 8192;
        int r = rem >> 13;
        int idx = rem & 8191;
        int n = idx >> 6, kp = idx & 63;
        const float* base = relw + (((size_t)(l * 8 + r) * 128) * 128) + n;
        float w0 = base[(size_t)(2 * kp) * 128];
        float w1 = base[(size_t)(2 * kp + 1) * 128];
        int pk = __builtin_amdgcn_cvt_pk_fp8_f32(w0, w1, 0, false);
        W8[gid] = (unsigned short)(pk & 0xffff);
    }
}

// ---------------- per-dst aggregation: 4 nodes per wave, fp8 out ----------------
// Quarter q (16 lanes) owns node 4w+q; lane j covers cols 8j..8j+7.
__global__ __launch_bounds__(256) void k_agg(
    const unsigned int* __restrict__ xin,   // [N][64] bf16x2
    const int* __restrict__ rowptr,         // [NR+1], seg = dst*8 + rel
    const int* __restrict__ srcs,           // [E] sorted by seg
    unsigned int* __restrict__ Ag8,         // [8][srows][32] fp8x4
    int d0, int rows, int srows)
{
    const int t = threadIdx.x;
    const int wv = t >> 6, lane = t & 63;
    const int q = lane >> 4, j = lane & 15;
    const int nb0 = (blockIdx.x * 4 + wv) * 4;     // first local node of this wave
    if (nb0 >= rows) return;
    const int myn = nb0 + q;
    const bool nvalid = (myn < rows);

    // preload rowptr[(d0+nb0)*8 + lane] for lane<33 (clamped)
    int pr = 0;
    {
        int idx = (d0 + nb0) * 8 + lane;
        if (idx > NR) idx = NR;
        if (lane < 33) pr = rowptr[idx];
    }
    const int P0 = __shfl(pr, 0);
    const int Dtot = __shfl(pr, 32) - P0;

    // lane l holds srcs[P0+l] (first 64 edges of the 4 nodes, contiguous)
    int my_src = 0;
    if (lane < Dtot) my_src = srcs[P0 + lane];

    const uint4* x4 = (const uint4*)xin;           // row = 16 uint4

    for (int r = 0; r < 8; ++r) {
        int e0 = __shfl(pr, q * 8 + r);
        int e1 = __shfl(pr, q * 8 + r + 1);
        int cnt = e1 - e0;                         // quarter-uniform
        int m1 = max(cnt, __shfl_xor(cnt, 16));
        int maxc = max(m1, __shfl_xor(m1, 32));    // wave max
        float a0 = 0.f, a1 = 0.f, a2 = 0.f, a3 = 0.f;
        float a4 = 0.f, a5 = 0.f, a6 = 0.f, a7 = 0.f;
        for (int k = 0; k < maxc; ++k) {
            int ei = e0 + k;
            int ridx = ei - P0;
            int s = __shfl(my_src, ridx & 63);
            if (ridx >= 64) s = srcs[ei];          // essentially never (Dtot<=64 w.h.p.)
            if (k < cnt) {
                uint4 u = x4[(size_t)s * 16 + j];
                a0 += bflo(u.x); a1 += bfhi(u.x);
                a2 += bflo(u.y); a3 += bfhi(u.y);
                a4 += bflo(u.z); a5 += bfhi(u.z);
                a6 += bflo(u.w); a7 += bfhi(u.w);
            }
        }
        float inv = (cnt > 0) ? 1.0f / (float)cnt : 0.f;
        int u0 = __builtin_amdgcn_cvt_pk_fp8_f32(a0 * inv, a1 * inv, 0, false);
        u0 = __builtin_amdgcn_cvt_pk_fp8_f32(a2 * inv, a3 * inv, u0, true);
        int u1 = __builtin_amdgcn_cvt_pk_fp8_f32(a4 * inv, a5 * inv, 0, false);
        u1 = __builtin_amdgcn_cvt_pk_fp8_f32(a6 * inv, a7 * inv, u1, true);
        if (nvalid) {
            uint2 v; v.x = (unsigned int)u0; v.y = (unsigned int)u1;
            *(uint2*)&Ag8[((size_t)r * srows + myn) * 32 + j * 2] = v;
        }
    }
}

// ---------------- dense MFMA GEMM, BM=128: 8 fp8 chunks + 1 bf16 root ----------------
#define BM 64
#define BM2 128
__global__ __launch_bounds__(256) void k_gemm(
    const unsigned int* __restrict__ Ag8,   // [8][srows][32] fp8x4
    const unsigned int* __restrict__ xin,   // [N][64] bf16x2 (root chunk)
    unsigned int* __restrict__ xout,        // [N][64] bf16x2
    const unsigned short* __restrict__ W8,  // [8][128n][64kp] fp8 pairs (this layer)
    const unsigned short* __restrict__ WT,  // [9][128n][128k] bf16 (this layer; root = chunk 8)
    const float* __restrict__ bias,         // [128]
    int d0, int srows)
{
    __shared__ __align__(16) unsigned long long Als[4096];  // 32 KB A region
    __shared__ __align__(16) unsigned long long Bls[4096];  // 32 KB B region
    const int t = threadIdx.x;
    const int wv = t >> 6, lane = t & 63;
    const int quad = lane >> 4, l15 = lane & 15;
    const int m0 = d0 + blockIdx.x * BM2;

    float4v acc[2][8];
#pragma unroll
    for (int nt = 0; nt < 8; ++nt) {
        float bc = bias[nt * 16 + l15];
        acc[0][nt] = (float4v){bc, bc, bc, bc};
        acc[1][nt] = (float4v){bc, bc, bc, bc};
    }

    // ---- 8 fp8 chunks: A 128x128B, B 128x128B ----
    for (int c = 0; c < 8; ++c) {
        __syncthreads();
        {
            const unsigned long long* Wc = (const unsigned long long*)(W8 + (size_t)c * 8192);
#pragma unroll
            for (int i = 0; i < 8; ++i) {
                int idx = t + 256 * i;            // 0..2047 granules
                Bls[gswz8(idx >> 4, idx & 15)] = Wc[idx];
            }
        }
        {
            const unsigned long long* Ac = (const unsigned long long*)(Ag8 + ((size_t)c * srows + (m0 - d0)) * 32);
#pragma unroll
            for (int i = 0; i < 8; ++i) {
                int idx = t + 256 * i;
                Als[gswz8(idx >> 4, idx & 15)] = Ac[idx];
            }
        }
        __syncthreads();
#pragma unroll
        for (int kk = 0; kk < 4; ++kk) {
            int g = kk * 4 + quad;
            long long a0 = (long long)Als[(wv * 32 + l15) * 16 + (g ^ l15)];
            long long a1 = (long long)Als[(wv * 32 + 16 + l15) * 16 + (g ^ l15)];
#pragma unroll
            for (int nt = 0; nt < 8; ++nt) {
                long long b8 = (long long)Bls[(nt * 16 + l15) * 16 + (g ^ l15)];
                acc[0][nt] = __builtin_amdgcn_mfma_f32_16x16x32_fp8_fp8(a0, b8, acc[0][nt], 0, 0, 0);
                acc[1][nt] = __builtin_amdgcn_mfma_f32_16x16x32_fp8_fp8(a1, b8, acc[1][nt], 0, 0, 0);
            }
        }
    }
    // ---- root chunk (bf16): A = xin rows (32 KB), B = WT chunk 8 (32 KB) ----
    __syncthreads();
    {
        uint4* A4 = (uint4*)Als;
        uint4* B4 = (uint4*)Bls;
        const uint4* Wc = (const uint4*)(WT + 8 * 16384);   // 2048 uint4
#pragma unroll
        for (int i = 0; i < 8; ++i) {
            int idx = t + 256 * i;
            B4[gswz(idx >> 4, idx & 15)] = Wc[idx];
        }
        const uint4* Ac = (const uint4*)(xin + (size_t)m0 * 64);  // 128 rows x 16 uint4
#pragma unroll
        for (int i = 0; i < 8; ++i) {
            int idx = t + 256 * i;
            A4[gswz(idx >> 4, idx & 15)] = Ac[idx];
        }
    }
    __syncthreads();
    {
        const unsigned short* Abfs = (const unsigned short*)Als;
        const unsigned short* Bbfs = (const unsigned short*)Bls;
#pragma unroll
        for (int kk = 0; kk < 4; ++kk) {
            int g = kk * 4 + quad;
            short8 a0 = *(const short8*)(Abfs + gswz(wv * 32 + l15, g) * 8);
            short8 a1 = *(const short8*)(Abfs + gswz(wv * 32 + 16 + l15, g) * 8);
#pragma unroll
            for (int nt = 0; nt < 8; ++nt) {
                short8 b = *(const short8*)(Bbfs + gswz(nt * 16 + l15, g) * 8);
                acc[0][nt] = __builtin_amdgcn_mfma_f32_16x16x32_bf16(a0, b, acc[0][nt], 0, 0, 0);
                acc[1][nt] = __builtin_amdgcn_mfma_f32_16x16x32_bf16(a1, b, acc[1][nt], 0, 0, 0);
            }
        }
    }
    // ---- epilogue: relu, store bf16 ----
    unsigned short* outs = (unsigned short*)xout;
#pragma unroll
    for (int rt = 0; rt < 2; ++rt) {
#pragma unroll
        for (int nt = 0; nt < 8; ++nt) {
            int colg = nt * 16 + l15;
#pragma unroll
            for (int i = 0; i < 4; ++i) {
                int row = m0 + wv * 32 + rt * 16 + quad * 4 + i;
                if (row < N_NODES) {
                    float v = acc[rt][nt][i];
                    v = v > 0.f ? v : 0.f;
                    outs[(size_t)row * 128 + colg] = f2bf(v);
                }
            }
        }
    }
}

// ---------------- FALLBACK (fused layer; used only if ws too small) ----------------
__global__ __launch_bounds__(256) void k_layer_fb(
    const unsigned int* __restrict__ xin, unsigned int* __restrict__ xout,
    const int* __restrict__ rowptr, const int* __restrict__ srcs,
    const unsigned short* __restrict__ WT, const float* __restrict__ bias)
{
    __shared__ __align__(16) unsigned int Als[BM * 68];
    __shared__ __align__(16) unsigned int Bls[128 * 68];
    const int t = threadIdx.x;
    const int wv = t >> 6, lane = t & 63;
    const int quad = lane >> 4, l15 = lane & 15;
    const int m0 = blockIdx.x * BM;
    const int col2 = t & 63;
    const int rq = t >> 6;

    float4v acc[8];
#pragma unroll
    for (int nt = 0; nt < 8; ++nt) {
        float bc = bias[nt * 16 + l15];
        acc[nt] = (float4v){bc, bc, bc, bc};
    }
    for (int c = 0; c < 9; ++c) {
        if (c < 8) {
            for (int i = 0; i < 16; ++i) {
                int ml = rq + 4 * i;
                int m = m0 + ml;
                float a0 = 0.f, a1 = 0.f, inv = 0.f;
                if (m < N_NODES) {
                    int seg = m * N_REL + c;
                    int s = rowptr[seg], e = rowptr[seg + 1];
                    if (e > s) inv = 1.0f / (float)(e - s);
                    for (int jj = s; jj < e; ++jj) {
                        unsigned int u = xin[(size_t)srcs[jj] * 64 + col2];
                        a0 += bflo(u);
                        a1 += bfhi(u);
                    }
                }
                Als[ml * 68 + col2] = pack2(a0 * inv, a1 * inv);
            }
        } else {
            for (int i = 0; i < 16; ++i) {
                int ml = rq + 4 * i;
                int m = m0 + ml;
                Als[ml * 68 + col2] = (m < N_NODES) ? xin[(size_t)m * 64 + col2] : 0u;
            }
        }
        {
            const unsigned int* Wc = (const unsigned int*)(WT + c * 16384);
#pragma unroll
            for (int i = 0; i < 32; ++i) {
                int idx = t + 256 * i;
                Bls[(idx >> 6) * 68 + (idx & 63)] = Wc[idx];
            }
        }
        __syncthreads();
        const short* As = (const short*)Als;
        const short* Bs = (const short*)Bls;
#pragma unroll
        for (int kk = 0; kk < 4; ++kk) {
            short8 a = *(const short8*)(As + (wv * 16 + l15) * 136 + kk * 32 + quad * 8);
#pragma unroll
            for (int nt = 0; nt < 8; ++nt) {
                short8 b = *(const short8*)(Bs + (nt * 16 + l15) * 136 + kk * 32 + quad * 8);
                acc[nt] = __builtin_amdgcn_mfma_f32_16x16x32_bf16(a, b, acc[nt], 0, 0, 0);
            }
        }
        __syncthreads();
    }
    unsigned short* outs = (unsigned short*)xout;
#pragma unroll
    for (int nt = 0; nt < 8; ++nt) {
        int colg = nt * 16 + l15;
#pragma unroll
        for (int i = 0; i < 4; ++i) {
            int row = m0 + wv * 16 + quad * 4 + i;
            if (row < N_NODES) {
                float v = acc[nt][i];
                v = v > 0.f ? v : 0.f;
                outs[(size_t)row * 128 + colg] = f2bf(v);
            }
        }
    }
}

// ---------------- global mean pool (batch sorted): 64 nodes per wave ----------------
__global__ __launch_bounds__(256) void k_pool(const unsigned int* __restrict__ x2,
                                              const int* __restrict__ batch,
                                              float* __restrict__ gsum,
                                              int* __restrict__ gcnt) {
    const int wv = threadIdx.x >> 6, lane = threadIdx.x & 63;
    const int n0 = (blockIdx.x * 4 + wv) * 64;
    if (n0 >= N_NODES) return;
    int n1 = n0 + 64;
    if (n1 > N_NODES) n1 = N_NODES;
    const int nb = n1 - n0;
    int bb = batch[n0 + (lane < nb ? lane : nb - 1)];
    float a0 = 0.f, a1 = 0.f;
    int run = 0;
    int cur = __shfl(bb, 0);
    for (int base = 0; base < nb; base += 8) {
        unsigned int u[8];
        int m = nb - base;
#pragma unroll
        for (int qq = 0; qq < 8; ++qq)
            if (qq < m) u[qq] = x2[(size_t)(n0 + base + qq) * 64 + lane];
#pragma unroll
        for (int qq = 0; qq < 8; ++qq) {
            if (qq < m) {
                int b = __shfl(bb, base + qq);
                if (b != cur) {
                    atomicAdd(&gsum[cur * 128 + lane * 2], a0);
                    atomicAdd(&gsum[cur * 128 + lane * 2 + 1], a1);
                    if (lane == 0) atomicAdd(&gcnt[cur], run);
                    a0 = a1 = 0.f;
                    run = 0;
                    cur = b;
                }
                a0 += bflo(u[qq]);
                a1 += bfhi(u[qq]);
                ++run;
            }
        }
    }
    atomicAdd(&gsum[cur * 128 + lane * 2], a0);
    atomicAdd(&gsum[cur * 128 + lane * 2 + 1], a1);
    if (lane == 0) atomicAdd(&gcnt[cur], run);
}

// ---------------- MLP heads (fp32) ----------------
__global__ __launch_bounds__(128) void k_heads(
    const float* __restrict__ gsum, const int* __restrict__ gcnt,
    const float* __restrict__ rw1, const float* __restrict__ rb1,
    const float* __restrict__ rw2, const float* __restrict__ rb2,
    const float* __restrict__ sw1, const float* __restrict__ sb1,
    const float* __restrict__ sw2, const float* __restrict__ sb2,
    float* __restrict__ out) {
    __shared__ float g[128];
    __shared__ float parts[2];
    int b = blockIdx.x, t = threadIdx.x;
    int c = gcnt[b];
    float invc = 1.0f / (float)(c > 0 ? c : 1);
    g[t] = gsum[b * 128 + t] * invc;
    __syncthreads();
    float acc = rb1[t];
    for (int d = 0; d < 128; ++d) acc += g[d] * rw1[d * 128 + t];
    float h = acc > 0.f ? acc : 0.f;
    float p = h * rw2[t];
    for (int o = 32; o > 0; o >>= 1) p += __shfl_down(p, o);
    if ((t & 63) == 0) parts[t >> 6] = p;
    __syncthreads();
    if (t == 0) out[b] = parts[0] + parts[1] + rb2[0];
    __syncthreads();
    acc = sb1[t];
    for (int d = 0; d < 128; ++d) acc += g[d] * sw1[d * 128 + t];
    h = acc > 0.f ? acc : 0.f;
    p = h * sw2[t];
    for (int o = 32; o > 0; o >>= 1) p += __shfl_down(p, o);
    if ((t & 63) == 0) parts[t >> 6] = p;
    __syncthreads();
    if (t == 0) out[64 + b] = parts[0] + parts[1] + sb2[0];
}

extern "C" void kernel_launch(void* const* d_in, const int* in_sizes, int n_in,
                              void* d_out, int out_size, void* d_ws, size_t ws_size,
                              hipStream_t stream) {
    const int*   node_type  = (const int*)d_in[0];
    const int*   edge_index = (const int*)d_in[1];
    const int*   edge_type  = (const int*)d_in[2];
    const int*   batch      = (const int*)d_in[3];
    const float* node_emb   = (const float*)d_in[4];
    const float* rel_w      = (const float*)d_in[5];
    const float* root_w     = (const float*)d_in[6];
    const float* bias       = (const float*)d_in[7];
    const float* rw1        = (const float*)d_in[8];
    const float* rb1        = (const float*)d_in[9];
    const float* rw2        = (const float*)d_in[10];
    const float* rb2        = (const float*)d_in[11];
    const float* sw1        = (const float*)d_in[12];
    const float* sb1        = (const float*)d_in[13];
    const float* sw2        = (const float*)d_in[14];
    const float* sb2        = (const float*)d_in[15];
    float* out = (float*)d_out;

    char* ws = (char*)d_ws;
    size_t off = 0;
    auto alloc = [&](size_t bytes) -> void* {
        void* p = ws + off;
        off += (bytes + 255) & ~(size_t)255;
        return p;
    };
    // ---- persistent region ----
    unsigned int*   xa     = (unsigned int*)alloc((size_t)N_NODES * 64 * 4);
    unsigned int*   xb     = (unsigned int*)alloc((size_t)N_NODES * 64 * 4);
    int*            rowptr = (int*)alloc((size_t)(NR + 1) * 4);
    int*            srcs   = (int*)alloc((size_t)N_EDGES * 4);
    int*            bsum   = (int*)alloc(1024 * 4);
    unsigned short* WT     = (unsigned short*)alloc((size_t)N_LAYER * 9 * 16384 * 2);
    unsigned short* W8     = (unsigned short*)alloc((size_t)N_LAYER * 8 * 8192 * 2);
    float*          gsum   = (float*)alloc((64 * 128 + 64) * 4);
    int*            gcnt   = (int*)(gsum + 64 * 128);
    size_t off_common = off;
    // ---- scratch region: sort temps, later overlapped by Ag8 slices ----
    int*            cursor = (int*)alloc((size_t)NR * 4);
    int*            counts = (int*)alloc((size_t)NR * 4);
    size_t off_sort = off;
    if (off_sort > ws_size) return;                // cannot run at all
    unsigned int*   Ag8    = (unsigned int*)(ws + off_common);  // overlaps cursor/counts
    size_t avail = ws_size - off_common;
    long max_rows = (avail > 32768) ? (long)((avail - 32768) / 1024) : 0;  // 32 KB tail-read slack
    int srows = (int)((max_rows / 64) * 64);
    if (srows > N_NODES + 63) srows = ((N_NODES + 63) / 64) * 64;
    const bool split_ok = (srows >= 128);

    // edge sort (counting sort by dst*8 + rel)
    k_zero<<<(NR + 255) / 256, 256, 0, stream>>>(counts, NR);
    k_zero<<<(64 * 128 + 64 + 255) / 256, 256, 0, stream>>>((int*)gsum, 64 * 128 + 64);
    k_hist<<<(N_EDGES + 255) / 256, 256, 0, stream>>>(edge_index, edge_type, counts);
    k_scan1<<<NB1, 256, 0, stream>>>(counts, cursor, bsum);
    k_scan2<<<1, 1024, 0, stream>>>(bsum, NB1);
    k_scan3<<<(NR + 255) / 256, 256, 0, stream>>>(cursor, bsum, rowptr, cursor);
    k_scatter<<<(N_EDGES + 255) / 256, 256, 0, stream>>>(edge_index, edge_type, cursor, srcs);

    // x0 gather + weight prep (bf16 + fp8)
    k_gather<<<(N_NODES * 64 + 255) / 256, 256, 0, stream>>>(node_type, node_emb, xa);
    k_wprep<<<(N_LAYER * 9 * 16384 + 255) / 256, 256, 0, stream>>>(rel_w, root_w, WT);
    k_wprep8<<<(N_LAYER * 8 * 8192 + 255) / 256, 256, 0, stream>>>(rel_w, W8);

    const int mblocks = (N_NODES + BM - 1) / BM;   // 1563 (fallback)
    unsigned int* xcur = xa;
    unsigned int* xnext = xb;
    for (int l = 0; l < N_LAYER; ++l) {
        const unsigned short* Wl  = WT + (size_t)l * 9 * 16384;
        const unsigned short* W8l = W8 + (size_t)l * 8 * 8192;
        const float* bl = bias + (size_t)l * 128;
        if (split_ok) {
            for (int d0 = 0; d0 < N_NODES; d0 += srows) {
                int rows = N_NODES - d0;
                if (rows > srows) rows = srows;
                int ab = (rows + 15) / 16;                 // 16 nodes per block (4 waves x 4)
                int gb = (rows + BM2 - 1) / BM2;
                k_agg<<<ab, 256, 0, stream>>>(xcur, rowptr, srcs, Ag8, d0, rows, srows);
                k_gemm<<<gb, 256, 0, stream>>>(Ag8, xcur, xnext, W8l, Wl, bl, d0, srows);
            }
        } else {
            k_layer_fb<<<mblocks, 256, 0, stream>>>(xcur, xnext, rowptr, srcs, Wl, bl);
        }
        unsigned int* tmp = xcur; xcur = xnext; xnext = tmp;
    }

    // pool + heads (final activations are in xcur after swap)
    k_pool<<<(N_NODES + 255) / 256, 256, 0, stream>>>(xcur, batch, gsum, gcnt);
    k_heads<<<64, 128, 0, stream>>>(gsum, gcnt, rw1, rb1, rw2, rb2,
                                    sw1, sb1, sw2, sb2, out);
}